// Round 18
// baseline (1938.647 us; speedup 1.0000x reference)
//
#include <hip/hip_runtime.h>
#include <hip/hip_bf16.h>
#include <math.h>

typedef __hip_bfloat16 bf16;
typedef unsigned short ushort;
typedef unsigned int u32;
typedef __attribute__((ext_vector_type(8))) short s8b;
typedef __attribute__((ext_vector_type(4))) short s4b;
typedef __attribute__((ext_vector_type(4))) float f4v;

#define Nc 1024
#define Dc 256
#define MA 4096

__device__ __forceinline__ float tofl(float v){ return v; }
__device__ __forceinline__ float tofl(bf16 v){ return __bfloat162float(v); }

__device__ __forceinline__ ushort rneu(float f){
  unsigned u = __float_as_uint(f);
  unsigned r = (u + 0x7fffu + ((u>>16)&1u)) >> 16;
  return (ushort)r;
}
__device__ __forceinline__ float ubf(ushort h){ return __uint_as_float(((unsigned)h)<<16); }

__device__ __forceinline__ float fexp2(float x){
#if __has_builtin(__builtin_amdgcn_exp2f)
  return __builtin_amdgcn_exp2f(x);
#else
  return exp2f(x);
#endif
}

// ---------------- dtype detect ----------------
__global__ void k_detect(const void* p, int* flag){
  if(threadIdx.x==0 && blockIdx.x==0){
    *flag = (((const ushort*)p)[0] == 0x3F80) ? 0 : 1;
  }
}

// ---------------- splits / casts ----------------
template<typename TIN>
__device__ void cast2_body(const void* in_, float* x, ushort* xh, ushort* xl, int n){
  const TIN* in = (const TIN*)in_;
  int i = blockIdx.x*256 + threadIdx.x;
  if(i >= n) return;
  float f = tofl(in[i]);
  x[i] = f;
  ushort h = rneu(f);
  xh[i] = h; xl[i] = rneu(f - ubf(h));
}
__global__ void k_cast2(const int* flag, const void* in, float* x, ushort* xh, ushort* xl, int n){
  if(*flag) cast2_body<float>(in, x, xh, xl, n); else cast2_body<bf16>(in, x, xh, xl, n);
}

template<typename TIN>
__device__ void splitw_body(const void* src_, long off, ushort* dh, ushort* dl, int n){
  const TIN* src = ((const TIN*)src_) + off;
  int i = blockIdx.x*256 + threadIdx.x;
  if(i >= n) return;
  float f = tofl(src[i]);
  ushort h = rneu(f);
  dh[i] = h; dl[i] = rneu(f - ubf(h));
}
__global__ void k_splitw(const int* flag, const void* src, long off, ushort* dh, ushort* dl, int n){
  if(*flag) splitw_body<float>(src, off, dh, dl, n); else splitw_body<bf16>(src, off, dh, dl, n);
}
template<typename TIN>
__device__ void biasf_body(const void* src_, long off, float* dst, int n){
  const TIN* src = ((const TIN*)src_) + off;
  int i = blockIdx.x*256 + threadIdx.x;
  if(i < n) dst[i] = tofl(src[i]);
}
__global__ void k_biasf(const int* flag, const void* src, long off, float* dst, int n){
  if(*flag) biasf_body<float>(src, off, dst, n); else biasf_body<bf16>(src, off, dst, n);
}

// ---------------- rotary cos/sin table: cs[m*64 + p*2 + {0,1}] --------------
template<typename TIN>
__device__ void rotcs_body(const void* kpts_, const void* Wr_, float* cs){
  int i = blockIdx.x*256 + threadIdx.x;     // m*32 + p
  if(i >= MA*32) return;
  int m = i >> 5, p = i & 31;
  const TIN* kpts = (const TIN*)kpts_;
  const TIN* Wr   = (const TIN*)Wr_;
  float kx = tofl(kpts[m*2]), ky = tofl(kpts[m*2+1]);
  float proj = kx*tofl(Wr[p*2]) + ky*tofl(Wr[p*2+1]);
  cs[(size_t)m*64 + p*2    ] = cosf(proj);
  cs[(size_t)m*64 + p*2 + 1] = sinf(proj);
}
__global__ void k_rotcs(const int* flag, const void* kpts, const void* Wr, float* cs){
  if(*flag) rotcs_body<float>(kpts, Wr, cs); else rotcs_body<bf16>(kpts, Wr, cs);
}

// per-layer weight split, 4-wide vectorized (blockIdx.y = layer offset)
// sWqkv rows PERMUTED: [q(256)|k(256)|v(256)].
// sOut_w / cOut_w slabs stored TRANSPOSED (only the fold GEMM reads them).
template<typename TIN>
__device__ void wsl_body(int L, const void* p0,const void* p1,const void* p2,const void* p3,
                         const void* p4,const void* p5,const void* p6,const void* p7,const void* p8,
                         const void* b0,const void* b1,const void* b2,const void* b3,const void* b4,
                         const void* b5,const void* b6,const void* b7,const void* b8,
                         ushort* WH, ushort* WL, float* WB){
  int idx = blockIdx.x*256 + threadIdx.x;
  if(idx < 311296){
    int i = idx*4;
    const TIN* s = nullptr;
    const TIN* tb = nullptr; int trow = 0, tcol = 0;
    if(i < 196608){
      int nr = i >> 8, col = i & 255;
      int sr = (nr < 256) ? nr*3 : (nr < 512) ? (nr-256)*3+1 : (nr-512)*3+2;
      s = (const TIN*)p0 + (size_t)L*196608 + sr*256 + col;
    }
    else if(i < 262144){ int li = i-196608; tb = (const TIN*)p1 + (size_t)L*65536; trow = li>>8; tcol = li&255; }
    else if(i < 524288)  s = (const TIN*)p2 + (size_t)L*262144 + (i-262144);
    else if(i < 655360)  s = (const TIN*)p3 + (size_t)L*131072 + (i-524288);
    else if(i < 720896)  s = (const TIN*)p4 + (size_t)L*65536  + (i-655360);
    else if(i < 786432)  s = (const TIN*)p5 + (size_t)L*65536  + (i-720896);
    else if(i < 851968){ int li = i-786432; tb = (const TIN*)p6 + (size_t)L*65536; trow = li>>8; tcol = li&255; }
    else if(i < 1114112) s = (const TIN*)p7 + (size_t)L*262144 + (i-851968);
    else                 s = (const TIN*)p8 + (size_t)L*131072 + (i-1114112);
    float f[4];
    if(tb){
#pragma unroll
      for(int j=0;j<4;j++) f[j] = tofl(tb[(size_t)(tcol+j)*256 + trow]);
    } else if constexpr(sizeof(TIN) == 4){
      f4v v = *(const f4v*)s;
      f[0]=v[0]; f[1]=v[1]; f[2]=v[2]; f[3]=v[3];
    } else {
      s4b v = *(const s4b*)s;
#pragma unroll
      for(int j=0;j<4;j++) f[j] = __uint_as_float(((u32)(ushort)v[j])<<16);
    }
    s4b hv, lv;
#pragma unroll
    for(int j=0;j<4;j++){
      ushort h = rneu(f[j]);
      hv[j] = (short)h;
      lv[j] = (short)rneu(f[j] - ubf(h));
    }
    *(s4b*)&WH[i] = hv;
    *(s4b*)&WL[i] = lv;
  } else if(idx < 311296 + 3328){
    int j = idx - 311296;
    const TIN* s;
    if(j < 768){
      int sj = (j < 256) ? j*3 : (j < 512) ? (j-256)*3+1 : (j-512)*3+2;
      s = (const TIN*)b0 + (size_t)L*768 + sj;
    }
    else if(j < 1024)  s = (const TIN*)b1 + (size_t)L*256 + (j-768);
    else if(j < 1536)  s = (const TIN*)b2 + (size_t)L*512 + (j-1024);
    else if(j < 1792)  s = (const TIN*)b3 + (size_t)L*256 + (j-1536);
    else if(j < 2048)  s = (const TIN*)b4 + (size_t)L*256 + (j-1792);
    else if(j < 2304)  s = (const TIN*)b5 + (size_t)L*256 + (j-2048);
    else if(j < 2560)  s = (const TIN*)b6 + (size_t)L*256 + (j-2304);
    else if(j < 3072)  s = (const TIN*)b7 + (size_t)L*512 + (j-2560);
    else               s = (const TIN*)b8 + (size_t)L*256 + (j-3072);
    WB[j] = tofl(*s);
  }
}
__global__ void k_wsplit(const int* flag, int L0, long strW, long strB,
    const void* p0,const void* p1,const void* p2,const void* p3,const void* p4,
    const void* p5,const void* p6,const void* p7,const void* p8,
    const void* b0,const void* b1,const void* b2,const void* b3,const void* b4,
    const void* b5,const void* b6,const void* b7,const void* b8,
    ushort* WH, ushort* WL, float* WB){
  int L = L0 + blockIdx.y;
  ushort* WHl = WH + (size_t)blockIdx.y*strW;
  ushort* WLl = WL + (size_t)blockIdx.y*strW;
  float*  WBl = WB + (size_t)blockIdx.y*strB;
  if(*flag) wsl_body<float>(L,p0,p1,p2,p3,p4,p5,p6,p7,p8,b0,b1,b2,b3,b4,b5,b6,b7,b8,WHl,WLl,WBl);
  else      wsl_body<bf16>(L,p0,p1,p2,p3,p4,p5,p6,p7,p8,b0,b1,b2,b3,b4,b5,b6,b7,b8,WHl,WLl,WBl);
}

// ---------------- bias fold: b1 += W1b @ bout (reads ORIGINAL W1b) ----------
// grid (8 strips of 64 rows, ncombo); 4 lanes per row, shuffle-reduced.
// hi/lo pair loads vectorized 4-wide.
__global__ __launch_bounds__(256)
void k_bcomb(const ushort* __restrict__ WH, const ushort* __restrict__ WL,
             float* WB, long strW, long strB){
  __shared__ float bo[256];
  int bx = blockIdx.x;
  int c = blockIdx.y;
  int L = c >> 1, br = c & 1;
  size_t wbase = (size_t)L*strW + (br ? 851968 : 262144);
  float* WBl = WB + (size_t)L*strB;
  float* b1 = WBl + (br ? 2560 : 1024);
  const float* bout = WBl + (br ? 2304 : 768);
  int t = threadIdx.x;
  bo[t] = bout[t];
  __syncthreads();
  int o = bx*64 + (t>>2);
  int p = t & 3;
  size_t rb = wbase + (size_t)o*512 + 256;
  float s = 0.f;
  for(int j=p*64; j<p*64+64; j+=4){
    s4b h4 = *(const s4b*)&WH[rb+j];
    s4b l4 = *(const s4b*)&WL[rb+j];
    f4v b4 = *(const f4v*)&bo[j];
    s += (ubf((ushort)h4[0])+ubf((ushort)l4[0]))*b4[0]
       + (ubf((ushort)h4[1])+ubf((ushort)l4[1]))*b4[1]
       + (ubf((ushort)h4[2])+ubf((ushort)l4[2]))*b4[2]
       + (ubf((ushort)h4[3])+ubf((ushort)l4[3]))*b4[3];
  }
  s += __shfl_xor(s,1);
  s += __shfl_xor(s,2);
  if(p==0) b1[o] += s;
}

// ---------------- MFMA split GEMM, MTx64 tile (MT=64 or 32), K/N-split waves ----
// single-buffer T14 prefetch. MT=32 doubles the grid for occupancy on
// grid-limited (N<=512) GEMMs.
// modes: 0 generic; 1 qkv (PERMUTED weights; FUSED ROTARY); 3 fused cQK|cV;
//        4 out-proj fold GEMM (Wout transposed, batched, writes over W1b);
//        6 batched sim scoring (two pairs via blockIdx.y>>5).
// vT blocks are written through an LDS transpose tile -> coalesced stores.
template<int MT>
__global__ __launch_bounds__(256)
void k_gemm_mxT(const ushort* __restrict__ Ah, const ushort* __restrict__ Al,
                const ushort* __restrict__ A2h, const ushort* __restrict__ A2l, int lda,
                const ushort* __restrict__ Bh, const ushort* __restrict__ Bl, int ldb,
                const float* __restrict__ bias, float alpha,
                float* C, int ldc, int accum,
                ushort* Ch, ushort* Cl, int lds,
                ushort* keh, ushort* kel, const float* __restrict__ cs,
                ushort* vth, ushort* vtl,
                int K, int mode){
  constexpr int MFR = MT/16;        // A frags per column strip
  constexpr int NACC = MFR*2;
  constexpr int MFH = MFR/2;        // frags per wave in epilogue
  __shared__ __align__(16) ushort LB[(2*MT+128)*72];
  int t = threadIdx.x;
  int n0 = blockIdx.x*64, m0 = blockIdx.y*MT;
  size_t wofs4 = 0;
  if(mode == 4){
    int by = blockIdx.y;
    int combo = by >> 4;            // 512/32 = 16 m-tiles per combo
    m0 = (by & 15) * MT;
    int Lc = combo >> 1, br = combo & 1;
    size_t basec = (size_t)Lc * (size_t)lds;   // lds carries strW
    wofs4 = basec + (br ? 851968 : 262144) + 256;
    size_t oofs = basec + (br ? 786432 : 196608);
    Bh = Ah + oofs; Bl = Al + oofs; ldb = 256;
    Ah = Ah + wofs4; Al = Al + wofs4; lda = 512;
  }
  if(mode == 6){
    int by = blockIdx.y;
    int p = by >> 5;
    m0 = (by & 31) * MT;
    size_t aofs = p ? (size_t)2048*256 : 0;
    size_t bofs = p ? (size_t)3072*256 : (size_t)1024*256;
    Bh = Ah + bofs; Bl = Al + bofs; ldb = 256;
    Ah += aofs; Al += aofs;
    C  = C + (size_t)p*1048576;
  }
  int w = t>>6, lane = t&63, quad = lane>>4, l15 = lane&15;
  int kg = w>>1, nh = w&1;
  int brow = t>>2, bc16 = (t&3)*16;           // B staging (64 rows)
  int arow = (MT==64) ? (t>>2) : (t>>3);      // A staging
  int acol = (MT==64) ? ((t&3)*16) : ((t&7)*8);
  f4v acc[NACC];
  f4v zz = {0.f,0.f,0.f,0.f};
#pragma unroll
  for(int j=0;j<NACC;j++) acc[j] = zz;
  int rounds = K >> 6;

  s8b r0,r1,r2,r3,r4,r5,r6,r7;
  auto gload = [&](int r){
    int k0 = r*64;
    const ushort* ah = Ah; const ushort* al = Al; int kloc = k0;
    if(A2h && k0 >= 256){ ah = A2h; al = A2l; kloc = k0 - 256; }
    const ushort* aph = &ah[(size_t)(m0+arow)*lda + kloc + acol];
    const ushort* apl = &al[(size_t)(m0+arow)*lda + kloc + acol];
    const ushort* bph = &Bh[(size_t)(n0+brow)*ldb + k0 + bc16];
    const ushort* bpl = &Bl[(size_t)(n0+brow)*ldb + k0 + bc16];
    r0 = *(const s8b*)aph;
    r2 = *(const s8b*)apl;
    if(MT==64){ r1 = *(const s8b*)(aph+8); r3 = *(const s8b*)(apl+8); }
    r4 = *(const s8b*)bph;   r5 = *(const s8b*)(bph+8);
    r6 = *(const s8b*)bpl;   r7 = *(const s8b*)(bpl+8);
  };
  auto writeS = [&](){
    *(s8b*)&LB[(arow)*72 + acol]        = r0;
    *(s8b*)&LB[(MT+arow)*72 + acol]     = r2;
    if(MT==64){
      *(s8b*)&LB[(arow)*72 + acol+8]    = r1;
      *(s8b*)&LB[(MT+arow)*72 + acol+8] = r3;
    }
    *(s8b*)&LB[(2*MT+brow)*72 + bc16]      = r4;
    *(s8b*)&LB[(2*MT+brow)*72 + bc16+8]    = r5;
    *(s8b*)&LB[(2*MT+64+brow)*72 + bc16]   = r6;
    *(s8b*)&LB[(2*MT+64+brow)*72 + bc16+8] = r7;
  };

  gload(0);
  for(int r=0; r<rounds; r++){
    __syncthreads();
    writeS();
    __syncthreads();
    s8b afh[MFR], afl[MFR], bfh[2], bfl[2];
#pragma unroll
    for(int mf=0;mf<MFR;mf++){
      afh[mf] = *(s8b*)&LB[(mf*16+l15)*72 + kg*32+quad*8];
      afl[mf] = *(s8b*)&LB[(MT+mf*16+l15)*72 + kg*32+quad*8];
    }
#pragma unroll
    for(int nf=0;nf<2;nf++){
      bfh[nf] = *(s8b*)&LB[(2*MT+nh*32+nf*16+l15)*72 + kg*32+quad*8];
      bfl[nf] = *(s8b*)&LB[(2*MT+64+nh*32+nf*16+l15)*72 + kg*32+quad*8];
    }
    if(r+1 < rounds) gload(r+1);
#pragma unroll
    for(int mf=0;mf<MFR;mf++){
#pragma unroll
      for(int nf=0;nf<2;nf++){
        int a = mf*2+nf;
        acc[a] = __builtin_amdgcn_mfma_f32_16x16x32_bf16(afh[mf], bfh[nf], acc[a], 0,0,0);
        acc[a] = __builtin_amdgcn_mfma_f32_16x16x32_bf16(afh[mf], bfl[nf], acc[a], 0,0,0);
        acc[a] = __builtin_amdgcn_mfma_f32_16x16x32_bf16(afl[mf], bfh[nf], acc[a], 0,0,0);
      }
    }
  }
  // cross-wave K-reduce: partner wave = w^2 (same nh, other kg)
  __syncthreads();
  f4v* scr = (f4v*)LB;
#pragma unroll
  for(int f=0;f<NACC;f++) scr[(w*NACC+f)*64 + lane] = acc[f];
  __syncthreads();
  int pw = w^2;
#pragma unroll
  for(int f=0;f<NACC;f++){
    f4v o = scr[(pw*NACC+f)*64 + lane];
    acc[f] += o;
  }

  // ---- vT-block epilogue via LDS transpose (block-uniform) ----
  bool vblk = (mode == 1 && n0 >= 512) || (mode == 3 && n0 >= 256);
  if(vblk){
    __syncthreads();
    u32* tp = (u32*)LB;                // [64 n][MT+1 m]
#pragma unroll
    for(int mi=0;mi<MFH;mi++){
      int mf = kg*MFH + mi;
#pragma unroll
      for(int nf=0;nf<2;nf++){
        f4v a = acc[mf*2+nf];
#pragma unroll
        for(int rr=0;rr<4;rr++){
          int ml = mf*16 + quad*4 + rr;
          int nl = nh*32 + nf*16 + l15;
          float val = a[rr];
          if(bias) val += bias[n0 + nl];
          val *= alpha;
          ushort hh = rneu(val);
          ushort ll = rneu(val - ubf(hh));
          tp[nl*(MT+1) + ml] = (u32)hh | ((u32)ll << 16);
        }
      }
    }
    __syncthreads();
    int b = m0 >> 10;
    int mloc = m0 & 1023;
    int d0 = n0 - ((mode == 1) ? 512 : 256);
    constexpr int NPASS = (MT==64) ? 2 : 1;
#pragma unroll
    for(int pass=0; pass<NPASS; pass++){
      int row, col;
      if(MT==64){ row = (t>>3) + pass*32; col = (t&7)*8; }
      else      { row = t>>2;             col = (t&3)*8; }
      int d = d0 + row;
      u32 c0=tp[row*(MT+1)+col+0], c1=tp[row*(MT+1)+col+1], c2=tp[row*(MT+1)+col+2], c3=tp[row*(MT+1)+col+3];
      u32 c4=tp[row*(MT+1)+col+4], c5=tp[row*(MT+1)+col+5], c6=tp[row*(MT+1)+col+6], c7=tp[row*(MT+1)+col+7];
      s8b hi, lo;
      hi[0]=(short)(c0&0xffff); lo[0]=(short)(c0>>16);
      hi[1]=(short)(c1&0xffff); lo[1]=(short)(c1>>16);
      hi[2]=(short)(c2&0xffff); lo[2]=(short)(c2>>16);
      hi[3]=(short)(c3&0xffff); lo[3]=(short)(c3>>16);
      hi[4]=(short)(c4&0xffff); lo[4]=(short)(c4>>16);
      hi[5]=(short)(c5&0xffff); lo[5]=(short)(c5>>16);
      hi[6]=(short)(c6&0xffff); lo[6]=(short)(c6>>16);
      hi[7]=(short)(c7&0xffff); lo[7]=(short)(c7>>16);
      size_t go = ((size_t)((b*4 + (d>>6))*64 + (d&63)))*1024 + mloc + col;
      *(s8b*)&vth[go] = hi;
      *(s8b*)&vtl[go] = lo;
    }
    return;
  }

  // ---- normal epilogue: wave handles its mf set, its nh half ----
#pragma unroll
  for(int mi=0;mi<MFH;mi++){
    int mf = kg*MFH + mi;
#pragma unroll
    for(int nf=0;nf<2;nf++){
      f4v a = acc[mf*2+nf];
#pragma unroll
      for(int rr=0;rr<4;rr++){
        int m = m0 + mf*16 + quad*4 + rr;
        int n = n0 + nh*32 + nf*16 + l15;
        float val = a[rr];
        if(bias) val += bias[n];
        val *= alpha;
        if(mode == 1){
          // fused rotary: pair partner lives in lane l15^1
          int d = (n < 256) ? n : (n - 256);
          const float* csp = cs + (size_t)m*64 + (d & 62);
          float cc = csp[0], ssn = csp[1];
          float pv = __shfl_xor(val, 1);
          float rv = (d & 1) ? (cc*val + ssn*pv) : (cc*val - ssn*pv);
          ushort hh = rneu(rv);
          ushort* dh = (n < 256) ? Ch : keh;
          ushort* dl = (n < 256) ? Cl : kel;
          size_t gi = (size_t)m*256 + d;
          dh[gi] = hh; dl[gi] = rneu(rv - ubf(hh));
        } else if(mode == 3){
          ushort hh = rneu(val);
          Ch[(size_t)m*256 + n] = hh;
          Cl[(size_t)m*256 + n] = rneu(val - ubf(hh));
        } else if(mode == 4){
          ushort hh = rneu(val);
          size_t gi = wofs4 + (size_t)m*512 + n;
          Ch[gi] = hh;
          Cl[gi] = rneu(val - ubf(hh));
        } else {
          if(C){
            size_t ci = (size_t)m*ldc + n;
            if(accum) val += C[ci];
            C[ci] = val;
          }
          if(Ch){
            ushort hh = rneu(val);
            Ch[(size_t)m*lds + n] = hh;
            Cl[(size_t)m*lds + n] = rneu(val - ubf(hh));
          }
        }
      }
    }
  }
}

// ---------------- MFMA flash attention, KV-chunked, split outputs ----------------
// Ps folded into wave-w's 16-row slice of Kh (K tile dead after QK^T).
// LDS = 36864 B -> 4 blocks/CU (full residency at grid 16x16x4).
#define FSC 0.18033688011112042f   /* 0.125 * log2(e) */
__global__ __launch_bounds__(256)
void k_flashmx(const ushort* __restrict__ qh_, const ushort* __restrict__ ql_,
               const ushort* __restrict__ kh_, const ushort* __restrict__ kl_,
               const ushort* __restrict__ vth_, const ushort* __restrict__ vtl_,
               ushort* __restrict__ cth, ushort* __restrict__ ctl, int bxor,
               float* __restrict__ PO, float* __restrict__ PML, int nch){
  int qt = blockIdx.x, z = blockIdx.y, ch = blockIdx.z;
  int b = z>>2, h = z&3;
  int bk = b ^ bxor;
  __shared__ __align__(16) ushort Kh[64][72], Kl[64][72], Vh[64][72], Vl[64][72];
  int t = threadIdx.x, w = t>>6, lane = t&63, quad = lane>>4, l15 = lane&15;
  ushort* Psw = &Kh[w*16][0];          // wave-private 16x72 slice of Kh
  s8b qfh[2], qfl[2];
  {
    size_t row = (size_t)b*1024 + qt*64 + w*16 + l15;
    const ushort* qrh = qh_ + row*256 + h*64;
    const ushort* qrl = ql_ + row*256 + h*64;
    qfh[0] = *(const s8b*)(qrh + quad*8);
    qfh[1] = *(const s8b*)(qrh + 32 + quad*8);
    qfl[0] = *(const s8b*)(qrl + quad*8);
    qfl[1] = *(const s8b*)(qrl + 32 + quad*8);
  }
  float m_i[4] = {-1e30f,-1e30f,-1e30f,-1e30f};
  float l_i[4] = {0.f,0.f,0.f,0.f};
  f4v O[4];
  f4v zz = {0.f,0.f,0.f,0.f};
#pragma unroll
  for(int dt=0;dt<4;dt++) O[dt] = zz;

  s8b rK0,rK1,rK2,rK3, rV0,rV1,rV2,rV3;
  auto stage_load = [&](int kt){
#pragma unroll
    for(int i=0;i<4;i++){
      int c = t + i*256;
      int half = c>>9, row = (c>>3)&63, o8 = (c&7)*8;
      const s8b* src = (const s8b*)((half ? kl_ : kh_) +
                       ((size_t)(bk*1024 + kt*64 + row))*256 + h*64 + o8);
      if(i==0) rK0=*src; else if(i==1) rK1=*src; else if(i==2) rK2=*src; else rK3=*src;
    }
#pragma unroll
    for(int i=0;i<4;i++){
      int c = t + i*256;
      int half = c>>9, d = (c>>3)&63, o8 = (c&7)*8;
      const s8b* src = (const s8b*)((half ? vtl_ : vth_) +
                       ((size_t)((bk*4+h)*64 + d))*1024 + kt*64 + o8);
      if(i==0) rV0=*src; else if(i==1) rV1=*src; else if(i==2) rV2=*src; else rV3=*src;
    }
  };
  auto stage_write = [&](){
#pragma unroll
    for(int i=0;i<4;i++){
      int c = t + i*256;
      int half = c>>9, row = (c>>3)&63, o8 = (c&7)*8;
      s8b v = (i==0)?rK0:(i==1)?rK1:(i==2)?rK2:rK3;
      if(half) *(s8b*)&Kl[row][o8] = v;
      else     *(s8b*)&Kh[row][o8] = v;
    }
#pragma unroll
    for(int i=0;i<4;i++){
      int c = t + i*256;
      int half = c>>9, d = (c>>3)&63, o8 = (c&7)*8;
      s8b v = (i==0)?rV0:(i==1)?rV1:(i==2)?rV2:rV3;
      if(half) *(s8b*)&Vl[d][o8] = v;
      else     *(s8b*)&Vh[d][o8] = v;
    }
  };

  int ktn = 16/nch;
  int kt0 = ch*ktn;
  stage_load(kt0);
  for(int kt=kt0; kt<kt0+ktn; kt++){
    __syncthreads();
    stage_write();
    __syncthreads();
    if(kt+1 < kt0+ktn) stage_load(kt+1);
    f4v s[4];
#pragma unroll
    for(int nt=0;nt<4;nt++) s[nt] = zz;
#pragma unroll
    for(int nt=0;nt<4;nt++){
#pragma unroll
      for(int k2=0;k2<2;k2++){
        s8b fbh = *(s8b*)&Kh[nt*16+l15][k2*32 + quad*8];
        s8b fbl = *(s8b*)&Kl[nt*16+l15][k2*32 + quad*8];
        s[nt] = __builtin_amdgcn_mfma_f32_16x16x32_bf16(qfh[k2], fbh, s[nt], 0,0,0);
        s[nt] = __builtin_amdgcn_mfma_f32_16x16x32_bf16(qfh[k2], fbl, s[nt], 0,0,0);
        s[nt] = __builtin_amdgcn_mfma_f32_16x16x32_bf16(qfl[k2], fbh, s[nt], 0,0,0);
      }
    }
    __syncthreads();   // all K reads done; Kh slices become P storage
#pragma unroll
    for(int rr=0;rr<4;rr++){
      float v0=s[0][rr]*FSC, v1=s[1][rr]*FSC, v2=s[2][rr]*FSC, v3=s[3][rr]*FSC;
      float mx = fmaxf(fmaxf(v0,v1), fmaxf(v2,v3));
      mx = fmaxf(mx, __shfl_xor(mx,1));
      mx = fmaxf(mx, __shfl_xor(mx,2));
      mx = fmaxf(mx, __shfl_xor(mx,4));
      mx = fmaxf(mx, __shfl_xor(mx,8));
      float mnew = fmaxf(m_i[rr], mx);
      float al = fexp2(m_i[rr] - mnew);
      float p0 = fexp2(v0-mnew), p1 = fexp2(v1-mnew), p2 = fexp2(v2-mnew), p3 = fexp2(v3-mnew);
      float ls = p0+p1+p2+p3;
      ls += __shfl_xor(ls,1);
      ls += __shfl_xor(ls,2);
      ls += __shfl_xor(ls,4);
      ls += __shfl_xor(ls,8);
      l_i[rr] = l_i[rr]*al + ls;
      m_i[rr] = mnew;
#pragma unroll
      for(int dt=0;dt<4;dt++) O[dt][rr] *= al;
      int prow = quad*4 + rr;
      Psw[prow*72 +  0 + l15] = rneu(p0);
      Psw[prow*72 + 16 + l15] = rneu(p1);
      Psw[prow*72 + 32 + l15] = rneu(p2);
      Psw[prow*72 + 48 + l15] = rneu(p3);
    }
    s8b pf0 = *(s8b*)&Psw[l15*72 + quad*8];
    s8b pf1 = *(s8b*)&Psw[l15*72 + 32 + quad*8];
#pragma unroll
    for(int dt=0;dt<4;dt++){
#pragma unroll
      for(int k2=0;k2<2;k2++){
        s8b fvh = *(s8b*)&Vh[dt*16+l15][k2*32 + quad*8];
        s8b fvl = *(s8b*)&Vl[dt*16+l15][k2*32 + quad*8];
        s8b pf = k2 ? pf1 : pf0;
        O[dt] = __builtin_amdgcn_mfma_f32_16x16x32_bf16(pf, fvh, O[dt], 0,0,0);
        O[dt] = __builtin_amdgcn_mfma_f32_16x16x32_bf16(pf, fvl, O[dt], 0,0,0);
      }
    }
  }
  if(nch == 1){
#pragma unroll
    for(int rr=0;rr<4;rr++){
      float inv = 1.f / l_i[rr];
      int row = qt*64 + w*16 + quad*4 + rr;
#pragma unroll
      for(int dt=0;dt<4;dt++){
        float val = O[dt][rr]*inv;
        size_t gi = ((size_t)b*1024 + row)*256 + h*64 + dt*16 + l15;
        ushort hh = rneu(val);
        cth[gi] = hh; ctl[gi] = rneu(val - ubf(hh));
      }
    }
  } else {
    size_t tb = (size_t)(z*16+qt)*nch + ch;
    float* po  = PO  + tb*4096;
    float* pml = PML + tb*128;
#pragma unroll
    for(int rr=0;rr<4;rr++){
      int row = w*16 + quad*4 + rr;
#pragma unroll
      for(int dt=0;dt<4;dt++){
        po[row*64 + dt*16 + l15] = O[dt][rr];
      }
      if(l15 == 0){
        pml[row]      = m_i[rr];
        pml[64 + row] = l_i[rr];
      }
    }
  }
}

// merge NCH=4 partials -> split bf16 output
__global__ __launch_bounds__(256)
void k_fmerge(const float* __restrict__ PO, const float* __restrict__ PML,
              ushort* __restrict__ cth, ushort* __restrict__ ctl){
  int qt = blockIdx.x, z = blockIdx.y;
  int b = z>>2, h = z&3;
  int t = threadIdx.x;
  int row = t>>2, dg = (t&3)*16;
  size_t tb0 = (size_t)(z*16+qt)*4;
  float m0 = PML[(tb0+0)*128 + row], m1 = PML[(tb0+1)*128 + row];
  float m2 = PML[(tb0+2)*128 + row], m3 = PML[(tb0+3)*128 + row];
  float M = fmaxf(fmaxf(m0,m1), fmaxf(m2,m3));
  float w0 = fexp2(m0-M), w1 = fexp2(m1-M), w2 = fexp2(m2-M), w3 = fexp2(m3-M);
  float L = PML[(tb0+0)*128 + 64 + row]*w0 + PML[(tb0+1)*128 + 64 + row]*w1
          + PML[(tb0+2)*128 + 64 + row]*w2 + PML[(tb0+3)*128 + 64 + row]*w3;
  float inv = 1.f/L;
  const f4v* p0 = (const f4v*)(PO + (tb0+0)*4096 + row*64 + dg);
  const f4v* p1 = (const f4v*)(PO + (tb0+1)*4096 + row*64 + dg);
  const f4v* p2 = (const f4v*)(PO + (tb0+2)*4096 + row*64 + dg);
  const f4v* p3 = (const f4v*)(PO + (tb0+3)*4096 + row*64 + dg);
  size_t gi = ((size_t)b*1024 + qt*64 + row)*256 + h*64 + dg;
#pragma unroll
  for(int j=0;j<4;j++){
    f4v o = p0[j]*w0 + p1[j]*w1 + p2[j]*w2 + p3[j]*w3;
#pragma unroll
    for(int e=0;e<4;e++){
      float val = o[e]*inv;
      ushort hh = rneu(val);
      cth[gi + j*4 + e] = hh;
      ctl[gi + j*4 + e] = rneu(val - ubf(hh));
    }
  }
}

// ---------------- LN(512)+GELU -> splits (wave-shuffle reduce) ----------------
template<typename TIN>
__device__ void ln2_body(const float* h, ushort* hh, ushort* hl, const TIN* g, const TIN* bb){
  __shared__ float ws8[8];
  int r = blockIdx.x; int t = threadIdx.x;
  int w = t>>6, lane = t&63;
  const float* row = h + (size_t)r*512;
  float a = row[t], b_ = row[t+256];
  float s = a + b_;
#pragma unroll
  for(int off=1; off<64; off<<=1) s += __shfl_xor(s, off);
  if(lane==0) ws8[w] = s;
  __syncthreads();
  float mean = (ws8[0]+ws8[1]+ws8[2]+ws8[3])*(1.f/512.f);
  float da = a-mean, db = b_-mean;
  float v = da*da + db*db;
#pragma unroll
  for(int off=1; off<64; off<<=1) v += __shfl_xor(v, off);
  if(lane==0) ws8[4+w] = v;
  __syncthreads();
  float rstd = rsqrtf((ws8[4]+ws8[5]+ws8[6]+ws8[7])*(1.f/512.f) + 1e-5f);
  float na = da*rstd*tofl(g[t])     + tofl(bb[t]);
  float nb = db*rstd*tofl(g[t+256]) + tofl(bb[t+256]);
  float ga = 0.5f*na*(1.f + erff(na*0.70710678f));
  float gb = 0.5f*nb*(1.f + erff(nb*0.70710678f));
  size_t base = (size_t)r*512;
  ushort u0 = rneu(ga); hh[base+t] = u0; hl[base+t] = rneu(ga - ubf(u0));
  ushort u1 = rneu(gb); hh[base+t+256] = u1; hl[base+t+256] = rneu(gb - ubf(u1));
}
__global__ void k_ln_gelu2(const int* flag, const float* h, ushort* hh, ushort* hl,
                           const void* gb, long goff, const void* bbb, long boff){
  if(*flag) ln2_body<float>(h, hh, hl, ((const float*)gb)+goff, ((const float*)bbb)+boff);
  else      ln2_body<bf16>(h, hh, hl, ((const bf16*)gb)+goff, ((const bf16*)bbb)+boff);
}

// ---------------- match head: z = x @ mw + mb, lsg = logsig(z) --------------
template<typename TIN>
__device__ void match_body(const float* x, const TIN* mw, const TIN* mb, float* lsg){
  __shared__ __align__(16) float wsm[256];
  int t = threadIdx.x;
  wsm[t] = tofl(mw[t]);
  __syncthreads();
  int w = t>>6, lane = t&63;
  int m = blockIdx.x*4 + w;
  const float* xr = x + (size_t)m*256 + lane*4;
  f4v xv = *(const f4v*)xr;
  f4v wv = *(const f4v*)&wsm[lane*4];
  float s = xv[0]*wv[0] + xv[1]*wv[1] + xv[2]*wv[2] + xv[3]*wv[3];
#pragma unroll
  for(int off=1; off<64; off<<=1) s += __shfl_xor(s, off);
  if(lane == 0){
    float z = s + tofl(mb[0]);
    lsg[m] = fminf(z,0.f) - log1pf(expf(-fabsf(z)));
  }
}
__global__ __launch_bounds__(256)
void k_match(const int* flag, const float* x, const void* mw, const void* mb, float* lsg){
  if(*flag) match_body<float>(x, (const float*)mw, (const float*)mb, lsg);
  else      match_body<bf16>(x, (const bf16*)mw, (const bf16*)mb, lsg);
}

// ---------------- scoring ----------------
// col-LSE stage 1: grid 512 (p=blk>>8, ci=blk&255), 4 rows each, no serial chain.
__global__ __launch_bounds__(256)
void k_lse_parts(const float* __restrict__ simbase, float* __restrict__ cpm,
                 float* __restrict__ cps){
  int blk = blockIdx.x;
  int p = blk >> 8, ci = blk & 255;
  const float* sim = simbase + (size_t)p*1048576 + (size_t)ci*4*1024;
  int t = threadIdx.x;
  size_t base = (size_t)(p*256 + ci)*1024;
#pragma unroll
  for(int j=0;j<4;j++){
    int col = t + j*256;
    float v0 = sim[col], v1 = sim[1024+col], v2 = sim[2048+col], v3 = sim[3072+col];
    float mx = fmaxf(fmaxf(v0,v1), fmaxf(v2,v3));
    float sm = expf(v0-mx)+expf(v1-mx)+expf(v2-mx)+expf(v3-mx);
    cpm[base+col] = mx;
    cps[base+col] = sm;
  }
}
// col-LSE stage 2: two passes (max then independent exps), grid 8.
__global__ __launch_bounds__(256)
void k_lse_merge(const float* __restrict__ cpm, const float* __restrict__ cps,
                 float* __restrict__ clseb){
  int blk = blockIdx.x;
  int p = blk >> 2, cg = blk & 3;
  int col = cg*256 + threadIdx.x;
  size_t base = (size_t)p*256*1024 + col;
  float M = -1e30f;
#pragma unroll 8
  for(int ci=0;ci<256;ci++) M = fmaxf(M, cpm[base + (size_t)ci*1024]);
  float s = 0.f;
#pragma unroll 8
  for(int ci=0;ci<256;ci++)
    s += cps[base + (size_t)ci*1024] * expf(cpm[base + (size_t)ci*1024] - M);
  clseb[p*1024 + col] = M + logf(s);
}

// final transform with FUSED row-LSE + fused row argmax (p==0 rows feed topk)
__global__ __launch_bounds__(256)
void k_final2r(float* __restrict__ out,
               const float* __restrict__ clse, const float* __restrict__ lsg,
               int* __restrict__ m0, float* __restrict__ msc){
  __shared__ float ws4[4];
  __shared__ float bsum[4];
  int blk = blockIdx.x;                 // 0..2047 = p*1024 + n
  int p = blk >> 10, n = blk & 1023;
  int t = threadIdx.x;
  int w = t>>6, lane = t&63;
  size_t base = (size_t)blk*1024;
  float v0 = out[base+t], v1 = out[base+t+256], v2 = out[base+t+512], v3 = out[base+t+768];
  // row max
  float mx = fmaxf(fmaxf(v0,v1),fmaxf(v2,v3));
#pragma unroll
  for(int off=1; off<64; off<<=1) mx = fmaxf(mx, __shfl_xor(mx, off));
  if(lane==0) ws4[w] = mx;
  __syncthreads();
  float bm = fmaxf(fmaxf(ws4[0],ws4[1]),fmaxf(ws4[2],ws4[3]));
  // row sum(exp)
  float s = expf(v0-bm)+expf(v1-bm)+expf(v2-bm)+expf(v3-bm);
#pragma unroll
  for(int off=1; off<64; off<<=1) s += __shfl_xor(s, off);
  if(lane==0) bsum[w] = s;
  __syncthreads();
  float rl = bm + logf(bsum[0]+bsum[1]+bsum[2]+bsum[3]);
  float lgn = lsg[p*2048 + n];
  const float* lgm = lsg + p*2048 + 1024;
  const float* cl = clse + p*1024;
  float bv = -1e30f; int bi = 0;
  float nv;
  int m;
  m = t;     nv = 2.f*v0 - rl - cl[m] + lgn + lgm[m]; out[base+m] = nv; if(nv > bv){ bv = nv; bi = m; }
  m = t+256; nv = 2.f*v1 - rl - cl[m] + lgn + lgm[m]; out[base+m] = nv; if(nv > bv){ bv = nv; bi = m; }
  m = t+512; nv = 2.f*v2 - rl - cl[m] + lgn + lgm[m]; out[base+m] = nv; if(nv > bv){ bv = nv; bi = m; }
  m = t+768; nv = 2.f*v3 - rl - cl[m] + lgn + lgm[m]; out[base+m] = nv; if(nv > bv){ bv = nv; bi = m; }
  if(p) return;
#pragma unroll
  for(int off=1; off<64; off<<=1){
    float v2_ = __shfl_xor(bv, off); int i2 = __shfl_xor(bi, off);
    if(v2_ > bv || (v2_ == bv && i2 < bi)){ bv = v2_; bi = i2; }
  }
  __shared__ float wv[4]; __shared__ int wi[4];
  if(lane==0){ wv[w]=bv; wi[w]=bi; }
  __syncthreads();
  if(t==0){
#pragma unroll
    for(int k=1;k<4;k++){
      if(wv[k] > wv[0] || (wv[k]==wv[0] && wi[k] < wi[0])){ wv[0]=wv[k]; wi[0]=wi[k]; }
    }
    m0[n] = wi[0]; msc[n] = expf(wv[0]);
  }
}

// col-argmax stage 1: grid 256, 4 rows each, strict > in ascending row order.
__global__ __launch_bounds__(256)
void k_amax_parts(const float* __restrict__ sc, float* __restrict__ apv,
                  int* __restrict__ api){
  int ci = blockIdx.x;
  const float* base = sc + (size_t)ci*4*1024;
  int t = threadIdx.x;
  size_t ob = (size_t)ci*1024;
#pragma unroll
  for(int j=0;j<4;j++){
    int col = t + j*256;
    float bv = base[col]; int bi = ci*4;
    float v1 = base[1024+col]; if(v1 > bv){ bv = v1; bi = ci*4+1; }
    float v2 = base[2048+col]; if(v2 > bv){ bv = v2; bi = ci*4+2; }
    float v3 = base[3072+col]; if(v3 > bv){ bv = v3; bi = ci*4+3; }
    apv[ob+col] = bv; api[ob+col] = bi;
  }
}
// col-argmax stage 2: merge ascending chunks (lowest n wins ties). grid 4.
__global__ __launch_bounds__(256)
void k_amax_merge(const float* __restrict__ apv, const int* __restrict__ api,
                  int* __restrict__ m1){
  int col = blockIdx.x*256 + threadIdx.x;
  float bv = -1e30f; int bi = 0;
#pragma unroll 8
  for(int ci=0;ci<256;ci++){
    float v = apv[(size_t)ci*1024 + col];
    if(v > bv){ bv = v; bi = api[(size_t)ci*1024 + col]; }
  }
  m1[col] = bi;
}

// ---------------- topk via global rank (parallel, exact tie semantics) -------
__global__ __launch_bounds__(128)
void k_topk(const int* __restrict__ m0, const int* __restrict__ m1,
            const float* __restrict__ msc, float* __restrict__ out){
  __shared__ float V[1024];
  int t = threadIdx.x;
  for(int i2=t; i2<1024; i2+=128){
    float mv = msc[i2];
    V[i2] = (mv > 0.1f && m1[m0[i2]] == i2) ? mv : 0.f;
  }
  __syncthreads();
  int i = blockIdx.x*128 + t;
  float vi = V[i];
  int r = 0;
#pragma unroll 8
  for(int j=0;j<1024;j++){
    float vj = V[j];
    r += (vj > vi || (vj == vi && j < i)) ? 1 : 0;
  }
  if(r < 50){
    out[2*Nc*Nc + r*3 + 0] = 0.f;
    out[2*Nc*Nc + r*3 + 1] = (float)i;
    out[2*Nc*Nc + r*3 + 2] = (float)m0[i];
    out[2*Nc*Nc + 150 + r] = vi;
  }
}

// ---------------- host ----------------
extern "C" void kernel_launch(void* const* d_in, const int* in_sizes, int n_in,
                              void* d_out, int out_size, void* d_ws, size_t ws_size,
                              hipStream_t stream){
  const void* kpts    = d_in[0];
  const void* desc    = d_in[1];
  const void* Wr      = d_in[2];
  const void* sWqkv_w = d_in[3];
  const void* sWqkv_b = d_in[4];
  const void* sOut_w  = d_in[5];
  const void* sOut_b  = d_in[6];
  const void* sF1_w   = d_in[7];
  const void* sF1_b   = d_in[8];
  const void* sLN_g   = d_in[9];
  const void* sLN_b   = d_in[10];
  const void* sF2_w   = d_in[11];
  const void* sF2_b   = d_in[12];
  const void* cQK_w   = d_in[13];
  const void* cQK_b   = d_in[14];
  const void* cV_w    = d_in[15];
  const void* cV_b    = d_in[16];
  const void* cOut_w  = d_in[17];
  const void* cOut_b  = d_in[18];
  const void* cF1_w   = d_in[19];
  const void* cF1_b   = d_in[20];
  const void* cLN_g   = d_in[21];
  const void* cLN_b   = d_in[22];
  const void* cF2_w   = d_in[23];
  const void* cF2_b   = d_in[24];
  const void* fp_w    = d_in[25];
  const void* fp_b    = d_in[26];
  const void* match_w = d_in[27];
  const void* match_b = d_in[28];

  float* ws  = (float*)d_ws;
  float* out = (float*)d_out;
  int* flag = (int*)d_ws;
  float* zbuf = ws + 64;
  float* clse = ws + 6208;
  float* msc  = ws + 12352;
  int*   m0i  = (int*)(ws + 13376);
  int*   m1i  = (int*)(ws + 14400);

  bool presplit = ws_size >= (size_t)20759552*4 + 1024;
  size_t wW = presplit ? 5603328 : 622592;
  size_t wB = presplit ? 32768   : 4096;

  size_t o = 16384;
  ushort* WH = (ushort*)(ws + o); o += wW;
  ushort* WL = (ushort*)(ws + o); o += wW;
  float*  WB = ws + o;            o += wB;
  ushort* fpWH = (ushort*)(ws + o); o += 32768;
  ushort* fpWL = (ushort*)(ws + o); o += 32768;
  float*  fpB  = ws + o;            o += 1024;
  float*  x  = ws + o;              o += 1048576;
  ushort* xh = (ushort*)(ws + o);   o += 524288;
  ushort* xl = (ushort*)(ws + o);   o += 524288;
  float*  hbuf = ws + o;            o += 2097152;
  ushort* qsh = (ushort*)(ws + o);  o += 524288;
  ushort* qsl = (ushort*)(ws + o);  o += 524288;
  ushort* ksh = (ushort*)(ws + o);  o += 524288;
  ushort* ksl = (ushort*)(ws + o);  o += 524288;
  ushort* vth = (ushort*)(ws + o);  o += 524288;
  ushort* vtl = (ushort*)(ws + o);  o += 524288;
  ushort* cth = (ushort*)(ws + o);  o += 524288;
  ushort* ctl = (ushort*)(ws + o);  o += 524288;
  ushort* mgh = (ushort*)(ws + o);  o += 524288;
  ushort* mgl = (ushort*)(ws + o);  o += 524288;
  ushort* hsh = qsh;
  ushort* hsl = ksh;
  ushort* mdh = cth;
  ushort* mdl = ctl;
  (void)mgh; (void)mgl;

  // rotary cos/sin table lives in the (not-yet-written) output buffer
  float* cs = out;   // 4096*64 floats, overwritten by final scoring

  // flash KV-split partials (16 z * 16 qt * 4 ch): PO 4096 f32/tile, PML 128 f32/tile
  float* PO  = ws + o;  // 4194304 floats
  float* PML = ws + o + 4194304;  // 131072 floats
  int nch = (ws_size >= (size_t)(20759552 + 4194304 + 131072)*4 + 1024) ? 4 : 1;

  // scoring scratch reuses PO (flash done before scoring)
  float* cpm = PO;                    // [2][256][1024]
  float* cps = PO + 524288;           // [2][256][1024]
  float* apv = PO + 1048576;          // [256][1024]
  int*   api = (int*)(PO + 1310720);  // [256][1024]

  auto MX = [&](const ushort* Ah, const ushort* Al, const ushort* A2h, const ushort* A2l,
                int lda, const ushort* Bh, const ushort* Bl, int ldb,
                const float* bias, float alpha, float* C, int ldc, int accum,
                ushort* Ch, ushort* Cl, int lds,
                ushort* keh, ushort* kel, ushort* vh, ushort* vl,
                int M, int Nout, int K, int mode, int mt){
    dim3 g(Nout/64, M/mt);
    if(mt == 32)
      k_gemm_mxT<32><<<g, 256, 0, stream>>>(Ah,Al,A2h,A2l,lda,Bh,Bl,ldb,bias,alpha,C,ldc,accum,
                                            Ch,Cl,lds,keh,kel,cs,vh,vl,K,mode);
    else
      k_gemm_mxT<64><<<g, 256, 0, stream>>>(Ah,Al,A2h,A2l,lda,Bh,Bl,ldb,bias,alpha,C,ldc,accum,
                                            Ch,Cl,lds,keh,kel,cs,vh,vl,K,mode);
  };
  auto FLASH = [&](const ushort* qh, const ushort* ql, const ushort* kh, const ushort* kl,
                   int bxor){
    k_flashmx<<<dim3(16,16,nch), 256, 0, stream>>>(qh,ql,kh,kl,vth,vtl, cth,ctl, bxor,
                                                   PO, PML, nch);
    if(nch == 4) k_fmerge<<<dim3(16,16), 256, 0, stream>>>(PO, PML, cth, ctl);
  };
  auto FOLD = [&](int ncombo, long strW){
    k_bcomb<<<dim3(8, ncombo), 256, 0, stream>>>(WH, WL, WB, strW, presplit ? 3328 : 0);
    k_gemm_mxT<32><<<dim3(4, ncombo*16), 256, 0, stream>>>(
        WH, WL, nullptr, nullptr, 0, nullptr, nullptr, 0,
        nullptr, 1.f, nullptr, 0, 0,
        WH, WL, (int)strW, nullptr, nullptr, cs, nullptr, nullptr, 256, 4);
  };

  k_detect<<<1, 64, 0, stream>>>(sLN_g, flag);
  k_splitw<<<(65536+255)/256, 256, 0, stream>>>(flag, fp_w, 0, fpWH, fpWL, 65536);
  k_biasf<<<1, 256, 0, stream>>>(flag, fp_b, 0, fpB, 256);
  k_cast2<<<(MA*Dc+255)/256, 256, 0, stream>>>(flag, desc, x, xh, xl, MA*Dc);
  k_rotcs<<<(MA*32+255)/256, 256, 0, stream>>>(flag, kpts, Wr, cs);

  if(presplit){
    dim3 g((311296+3328+255)/256, 9);
    k_wsplit<<<g, 256, 0, stream>>>(flag, 0, 1245184, 3328,
      sWqkv_w, sOut_w, sF1_w, sF2_w, cQK_w, cV_w, cOut_w, cF1_w, cF2_w,
      sWqkv_b, sOut_b, sF1_b, sF2_b, cQK_b, cV_b, cOut_b, cF1_b, cF2_b,
      WH, WL, WB);
    FOLD(18, 1245184);
  }

  for(int i=0;i<9;i++){
    if(!presplit){
      dim3 g((311296+3328+255)/256, 1);
      k_wsplit<<<g, 256, 0, stream>>>(flag, i, 0, 0,
        sWqkv_w, sOut_w, sF1_w, sF2_w, cQK_w, cV_w, cOut_w, cF1_w, cF2_w,
        sWqkv_b, sOut_b, sF1_b, sF2_b, cQK_b, cV_b, cOut_b, cF1_b, cF2_b,
        WH, WL, WB);
      FOLD(2, 0);
    }
    const ushort* WHl = presplit ? WH + (size_t)i*1245184 : WH;
    const ushort* WLl = presplit ? WL + (size_t)i*1245184 : WL;
    const float*  WBl = presplit ? WB + (size_t)i*3328    : WB;

    // ---- self (rotary fused into QKV epilogue; out-proj folded into FFN1) ----
    MX(xh,xl,nullptr,nullptr,256, WHl+0,WLl+0,256, WBl+0, 1.f,
       nullptr,0,0, qsh,qsl,0, ksh,ksl, vth,vtl, MA,768,256, 1, 32);
    FLASH(qsh,qsl,ksh,ksl, 0);
    MX(xh,xl,cth,ctl,256, WHl+262144,WLl+262144,512, WBl+1024, 1.f,
       hbuf,512,0, nullptr,nullptr,0, nullptr,nullptr, nullptr,nullptr, MA,512,512, 0, 32);
    k_ln_gelu2<<<MA, 256, 0, stream>>>(flag, hbuf, hsh, hsl, sLN_g, (long)i*512, sLN_b, (long)i*512);
    MX(hsh,hsl,nullptr,nullptr,512, WHl+524288,WLl+524288,512, WBl+1536, 1.f,
       x,256,1, xh,xl,256, nullptr,nullptr, nullptr,nullptr, MA,256,512, 0, 32);
    // ---- cross (cQK + cV fused; out-proj folded into FFN1) ----
    MX(xh,xl,nullptr,nullptr,256, WHl+655360,WLl+655360,256, WBl+1792, 1.f,
       nullptr,0,0, qsh,qsl,0, nullptr,nullptr, vth,vtl, MA,512,256, 3, 32);
    FLASH(qsh,qsl,qsh,qsl, 1);
    MX(xh,xl,cth,ctl,256, WHl+851968,WLl+851968,512, WBl+2560, 1.f,
       hbuf,512,0, nullptr,nullptr,0, nullptr,nullptr, nullptr,nullptr, MA,512,512, 0, 32);
    k_ln_gelu2<<<MA, 256, 0, stream>>>(flag, hbuf, hsh, hsl, cLN_g, (long)i*512, cLN_b, (long)i*512);
    MX(hsh,hsl,nullptr,nullptr,512, WHl+1114112,WLl+1114112,512, WBl+3072, 1.f,
       x,256,1, xh,xl,256, nullptr,nullptr, nullptr,nullptr, MA,256,512, 0, 32);
  }

  // ---- final scoring ----
  MX(xh,xl,nullptr,nullptr,256, fpWH,fpWL,256, fpB, 0.25f,
     nullptr,0,0, mdh,mdl,256, nullptr,nullptr, nullptr,nullptr, MA,256,256, 0, 32);
  k_match<<<1024, 256, 0, stream>>>(flag, x, match_w, match_b, zbuf);
  // both sim GEMMs in one batched dispatch (mode 6)
  k_gemm_mxT<32><<<dim3(16, 64), 256, 0, stream>>>(
      mdh, mdl, nullptr, nullptr, 256,
      mdh, mdl, 256,
      nullptr, 1.f, out, 1024, 0,
      nullptr, nullptr, 0,
      nullptr, nullptr, cs, nullptr, nullptr, 256, 6);

  k_lse_parts<<<512, 256, 0, stream>>>(out, cpm, cps);
  k_lse_merge<<<8, 256, 0, stream>>>(cpm, cps, clse);
  k_final2r<<<2048, 256, 0, stream>>>(out, clse, zbuf, m0i, msc);
  k_amax_parts<<<256, 256, 0, stream>>>(out, apv, api);
  k_amax_merge<<<4, 256, 0, stream>>>(apv, api, m1i);
  k_topk<<<8, 128, 0, stream>>>(m0i, m1i, msc, out);
}

// Round 19
// 1808.756 us; speedup vs baseline: 1.0718x; 1.0718x over previous
//
#include <hip/hip_runtime.h>
#include <hip/hip_bf16.h>
#include <math.h>

typedef __hip_bfloat16 bf16;
typedef unsigned short ushort;
typedef unsigned int u32;
typedef __attribute__((ext_vector_type(8))) short s8b;
typedef __attribute__((ext_vector_type(4))) short s4b;
typedef __attribute__((ext_vector_type(4))) float f4v;

#define Nc 1024
#define Dc 256
#define MA 4096

__device__ __forceinline__ float tofl(float v){ return v; }
__device__ __forceinline__ float tofl(bf16 v){ return __bfloat162float(v); }

__device__ __forceinline__ ushort rneu(float f){
  unsigned u = __float_as_uint(f);
  unsigned r = (u + 0x7fffu + ((u>>16)&1u)) >> 16;
  return (ushort)r;
}
__device__ __forceinline__ float ubf(ushort h){ return __uint_as_float(((unsigned)h)<<16); }

__device__ __forceinline__ float fexp2(float x){
#if __has_builtin(__builtin_amdgcn_exp2f)
  return __builtin_amdgcn_exp2f(x);
#else
  return exp2f(x);
#endif
}

// ---------------- dtype detect ----------------
__global__ void k_detect(const void* p, int* flag){
  if(threadIdx.x==0 && blockIdx.x==0){
    *flag = (((const ushort*)p)[0] == 0x3F80) ? 0 : 1;
  }
}

// ---------------- splits / casts ----------------
template<typename TIN>
__device__ void cast2_body(const void* in_, float* x, ushort* xh, ushort* xl, int n){
  const TIN* in = (const TIN*)in_;
  int i = blockIdx.x*256 + threadIdx.x;
  if(i >= n) return;
  float f = tofl(in[i]);
  x[i] = f;
  ushort h = rneu(f);
  xh[i] = h; xl[i] = rneu(f - ubf(h));
}
__global__ void k_cast2(const int* flag, const void* in, float* x, ushort* xh, ushort* xl, int n){
  if(*flag) cast2_body<float>(in, x, xh, xl, n); else cast2_body<bf16>(in, x, xh, xl, n);
}

template<typename TIN>
__device__ void splitw_body(const void* src_, long off, ushort* dh, ushort* dl, int n){
  const TIN* src = ((const TIN*)src_) + off;
  int i = blockIdx.x*256 + threadIdx.x;
  if(i >= n) return;
  float f = tofl(src[i]);
  ushort h = rneu(f);
  dh[i] = h; dl[i] = rneu(f - ubf(h));
}
__global__ void k_splitw(const int* flag, const void* src, long off, ushort* dh, ushort* dl, int n){
  if(*flag) splitw_body<float>(src, off, dh, dl, n); else splitw_body<bf16>(src, off, dh, dl, n);
}
template<typename TIN>
__device__ void biasf_body(const void* src_, long off, float* dst, int n){
  const TIN* src = ((const TIN*)src_) + off;
  int i = blockIdx.x*256 + threadIdx.x;
  if(i < n) dst[i] = tofl(src[i]);
}
__global__ void k_biasf(const int* flag, const void* src, long off, float* dst, int n){
  if(*flag) biasf_body<float>(src, off, dst, n); else biasf_body<bf16>(src, off, dst, n);
}

// ---------------- rotary cos/sin table: cs[m*64 + p*2 + {0,1}] --------------
template<typename TIN>
__device__ void rotcs_body(const void* kpts_, const void* Wr_, float* cs){
  int i = blockIdx.x*256 + threadIdx.x;     // m*32 + p
  if(i >= MA*32) return;
  int m = i >> 5, p = i & 31;
  const TIN* kpts = (const TIN*)kpts_;
  const TIN* Wr   = (const TIN*)Wr_;
  float kx = tofl(kpts[m*2]), ky = tofl(kpts[m*2+1]);
  float proj = kx*tofl(Wr[p*2]) + ky*tofl(Wr[p*2+1]);
  cs[(size_t)m*64 + p*2    ] = cosf(proj);
  cs[(size_t)m*64 + p*2 + 1] = sinf(proj);
}
__global__ void k_rotcs(const int* flag, const void* kpts, const void* Wr, float* cs){
  if(*flag) rotcs_body<float>(kpts, Wr, cs); else rotcs_body<bf16>(kpts, Wr, cs);
}

// per-layer weight split, 4-wide vectorized (blockIdx.y = layer offset)
// sWqkv rows PERMUTED: [q(256)|k(256)|v(256)].
// sOut_w / cOut_w slabs stored TRANSPOSED (only the fold GEMM reads them).
template<typename TIN>
__device__ void wsl_body(int L, const void* p0,const void* p1,const void* p2,const void* p3,
                         const void* p4,const void* p5,const void* p6,const void* p7,const void* p8,
                         const void* b0,const void* b1,const void* b2,const void* b3,const void* b4,
                         const void* b5,const void* b6,const void* b7,const void* b8,
                         ushort* WH, ushort* WL, float* WB){
  int idx = blockIdx.x*256 + threadIdx.x;
  if(idx < 311296){
    int i = idx*4;
    const TIN* s = nullptr;
    const TIN* tb = nullptr; int trow = 0, tcol = 0;
    if(i < 196608){
      int nr = i >> 8, col = i & 255;
      int sr = (nr < 256) ? nr*3 : (nr < 512) ? (nr-256)*3+1 : (nr-512)*3+2;
      s = (const TIN*)p0 + (size_t)L*196608 + sr*256 + col;
    }
    else if(i < 262144){ int li = i-196608; tb = (const TIN*)p1 + (size_t)L*65536; trow = li>>8; tcol = li&255; }
    else if(i < 524288)  s = (const TIN*)p2 + (size_t)L*262144 + (i-262144);
    else if(i < 655360)  s = (const TIN*)p3 + (size_t)L*131072 + (i-524288);
    else if(i < 720896)  s = (const TIN*)p4 + (size_t)L*65536  + (i-655360);
    else if(i < 786432)  s = (const TIN*)p5 + (size_t)L*65536  + (i-720896);
    else if(i < 851968){ int li = i-786432; tb = (const TIN*)p6 + (size_t)L*65536; trow = li>>8; tcol = li&255; }
    else if(i < 1114112) s = (const TIN*)p7 + (size_t)L*262144 + (i-851968);
    else                 s = (const TIN*)p8 + (size_t)L*131072 + (i-1114112);
    float f[4];
    if(tb){
#pragma unroll
      for(int j=0;j<4;j++) f[j] = tofl(tb[(size_t)(tcol+j)*256 + trow]);
    } else if constexpr(sizeof(TIN) == 4){
      f4v v = *(const f4v*)s;
      f[0]=v[0]; f[1]=v[1]; f[2]=v[2]; f[3]=v[3];
    } else {
      s4b v = *(const s4b*)s;
#pragma unroll
      for(int j=0;j<4;j++) f[j] = __uint_as_float(((u32)(ushort)v[j])<<16);
    }
    s4b hv, lv;
#pragma unroll
    for(int j=0;j<4;j++){
      ushort h = rneu(f[j]);
      hv[j] = (short)h;
      lv[j] = (short)rneu(f[j] - ubf(h));
    }
    *(s4b*)&WH[i] = hv;
    *(s4b*)&WL[i] = lv;
  } else if(idx < 311296 + 3328){
    int j = idx - 311296;
    const TIN* s;
    if(j < 768){
      int sj = (j < 256) ? j*3 : (j < 512) ? (j-256)*3+1 : (j-512)*3+2;
      s = (const TIN*)b0 + (size_t)L*768 + sj;
    }
    else if(j < 1024)  s = (const TIN*)b1 + (size_t)L*256 + (j-768);
    else if(j < 1536)  s = (const TIN*)b2 + (size_t)L*512 + (j-1024);
    else if(j < 1792)  s = (const TIN*)b3 + (size_t)L*256 + (j-1536);
    else if(j < 2048)  s = (const TIN*)b4 + (size_t)L*256 + (j-1792);
    else if(j < 2304)  s = (const TIN*)b5 + (size_t)L*256 + (j-2048);
    else if(j < 2560)  s = (const TIN*)b6 + (size_t)L*256 + (j-2304);
    else if(j < 3072)  s = (const TIN*)b7 + (size_t)L*512 + (j-2560);
    else               s = (const TIN*)b8 + (size_t)L*256 + (j-3072);
    WB[j] = tofl(*s);
  }
}
__global__ void k_wsplit(const int* flag, int L0, long strW, long strB,
    const void* p0,const void* p1,const void* p2,const void* p3,const void* p4,
    const void* p5,const void* p6,const void* p7,const void* p8,
    const void* b0,const void* b1,const void* b2,const void* b3,const void* b4,
    const void* b5,const void* b6,const void* b7,const void* b8,
    ushort* WH, ushort* WL, float* WB){
  int L = L0 + blockIdx.y;
  ushort* WHl = WH + (size_t)blockIdx.y*strW;
  ushort* WLl = WL + (size_t)blockIdx.y*strW;
  float*  WBl = WB + (size_t)blockIdx.y*strB;
  if(*flag) wsl_body<float>(L,p0,p1,p2,p3,p4,p5,p6,p7,p8,b0,b1,b2,b3,b4,b5,b6,b7,b8,WHl,WLl,WBl);
  else      wsl_body<bf16>(L,p0,p1,p2,p3,p4,p5,p6,p7,p8,b0,b1,b2,b3,b4,b5,b6,b7,b8,WHl,WLl,WBl);
}

// ---------------- bias fold: b1 += W1b @ bout (reads ORIGINAL W1b) ----------
// grid (8 strips of 64 rows, ncombo); 4 lanes per row, shuffle-reduced.
// hi/lo pair loads vectorized 4-wide.
__global__ __launch_bounds__(256)
void k_bcomb(const ushort* __restrict__ WH, const ushort* __restrict__ WL,
             float* WB, long strW, long strB){
  __shared__ float bo[256];
  int bx = blockIdx.x;
  int c = blockIdx.y;
  int L = c >> 1, br = c & 1;
  size_t wbase = (size_t)L*strW + (br ? 851968 : 262144);
  float* WBl = WB + (size_t)L*strB;
  float* b1 = WBl + (br ? 2560 : 1024);
  const float* bout = WBl + (br ? 2304 : 768);
  int t = threadIdx.x;
  bo[t] = bout[t];
  __syncthreads();
  int o = bx*64 + (t>>2);
  int p = t & 3;
  size_t rb = wbase + (size_t)o*512 + 256;
  float s = 0.f;
  for(int j=p*64; j<p*64+64; j+=4){
    s4b h4 = *(const s4b*)&WH[rb+j];
    s4b l4 = *(const s4b*)&WL[rb+j];
    f4v b4 = *(const f4v*)&bo[j];
    s += (ubf((ushort)h4[0])+ubf((ushort)l4[0]))*b4[0]
       + (ubf((ushort)h4[1])+ubf((ushort)l4[1]))*b4[1]
       + (ubf((ushort)h4[2])+ubf((ushort)l4[2]))*b4[2]
       + (ubf((ushort)h4[3])+ubf((ushort)l4[3]))*b4[3];
  }
  s += __shfl_xor(s,1);
  s += __shfl_xor(s,2);
  if(p==0) b1[o] += s;
}

// ---------------- MFMA split GEMM, MTx64 tile (MT=64 or 32), K/N-split waves ----
// single-buffer T14 prefetch. MT=32 doubles the grid for occupancy on
// grid-limited (N<=512) GEMMs.
// modes: 0 generic; 1 qkv (PERMUTED weights; FUSED ROTARY); 3 fused cQK|cV;
//        4 out-proj fold GEMM (Wout transposed, batched, writes over W1b);
//        6 batched sim scoring (two pairs via blockIdx.y>>5).
// vT blocks are written through an LDS transpose tile -> coalesced stores.
template<int MT>
__global__ __launch_bounds__(256)
void k_gemm_mxT(const ushort* __restrict__ Ah, const ushort* __restrict__ Al,
                const ushort* __restrict__ A2h, const ushort* __restrict__ A2l, int lda,
                const ushort* __restrict__ Bh, const ushort* __restrict__ Bl, int ldb,
                const float* __restrict__ bias, float alpha,
                float* C, int ldc, int accum,
                ushort* Ch, ushort* Cl, int lds,
                ushort* keh, ushort* kel, const float* __restrict__ cs,
                ushort* vth, ushort* vtl,
                int K, int mode){
  constexpr int MFR = MT/16;        // A frags per column strip
  constexpr int NACC = MFR*2;
  constexpr int MFH = MFR/2;        // frags per wave in epilogue
  __shared__ __align__(16) ushort LB[(2*MT+128)*72];
  int t = threadIdx.x;
  int n0 = blockIdx.x*64, m0 = blockIdx.y*MT;
  size_t wofs4 = 0;
  if(mode == 4){
    int by = blockIdx.y;
    int combo = by >> 4;            // 512/32 = 16 m-tiles per combo
    m0 = (by & 15) * MT;
    int Lc = combo >> 1, br = combo & 1;
    size_t basec = (size_t)Lc * (size_t)lds;   // lds carries strW
    wofs4 = basec + (br ? 851968 : 262144) + 256;
    size_t oofs = basec + (br ? 786432 : 196608);
    Bh = Ah + oofs; Bl = Al + oofs; ldb = 256;
    Ah = Ah + wofs4; Al = Al + wofs4; lda = 512;
  }
  if(mode == 6){
    int by = blockIdx.y;
    int p = by >> 5;
    m0 = (by & 31) * MT;
    size_t aofs = p ? (size_t)2048*256 : 0;
    size_t bofs = p ? (size_t)3072*256 : (size_t)1024*256;
    Bh = Ah + bofs; Bl = Al + bofs; ldb = 256;
    Ah += aofs; Al += aofs;
    C  = C + (size_t)p*1048576;
  }
  int w = t>>6, lane = t&63, quad = lane>>4, l15 = lane&15;
  int kg = w>>1, nh = w&1;
  int brow = t>>2, bc16 = (t&3)*16;           // B staging (64 rows)
  int arow = (MT==64) ? (t>>2) : (t>>3);      // A staging
  int acol = (MT==64) ? ((t&3)*16) : ((t&7)*8);
  f4v acc[NACC];
  f4v zz = {0.f,0.f,0.f,0.f};
#pragma unroll
  for(int j=0;j<NACC;j++) acc[j] = zz;
  int rounds = K >> 6;

  s8b r0,r1,r2,r3,r4,r5,r6,r7;
  auto gload = [&](int r){
    int k0 = r*64;
    const ushort* ah = Ah; const ushort* al = Al; int kloc = k0;
    if(A2h && k0 >= 256){ ah = A2h; al = A2l; kloc = k0 - 256; }
    const ushort* aph = &ah[(size_t)(m0+arow)*lda + kloc + acol];
    const ushort* apl = &al[(size_t)(m0+arow)*lda + kloc + acol];
    const ushort* bph = &Bh[(size_t)(n0+brow)*ldb + k0 + bc16];
    const ushort* bpl = &Bl[(size_t)(n0+brow)*ldb + k0 + bc16];
    r0 = *(const s8b*)aph;
    r2 = *(const s8b*)apl;
    if(MT==64){ r1 = *(const s8b*)(aph+8); r3 = *(const s8b*)(apl+8); }
    r4 = *(const s8b*)bph;   r5 = *(const s8b*)(bph+8);
    r6 = *(const s8b*)bpl;   r7 = *(const s8b*)(bpl+8);
  };
  auto writeS = [&](){
    *(s8b*)&LB[(arow)*72 + acol]        = r0;
    *(s8b*)&LB[(MT+arow)*72 + acol]     = r2;
    if(MT==64){
      *(s8b*)&LB[(arow)*72 + acol+8]    = r1;
      *(s8b*)&LB[(MT+arow)*72 + acol+8] = r3;
    }
    *(s8b*)&LB[(2*MT+brow)*72 + bc16]      = r4;
    *(s8b*)&LB[(2*MT+brow)*72 + bc16+8]    = r5;
    *(s8b*)&LB[(2*MT+64+brow)*72 + bc16]   = r6;
    *(s8b*)&LB[(2*MT+64+brow)*72 + bc16+8] = r7;
  };

  gload(0);
  for(int r=0; r<rounds; r++){
    __syncthreads();
    writeS();
    __syncthreads();
    s8b afh[MFR], afl[MFR], bfh[2], bfl[2];
#pragma unroll
    for(int mf=0;mf<MFR;mf++){
      afh[mf] = *(s8b*)&LB[(mf*16+l15)*72 + kg*32+quad*8];
      afl[mf] = *(s8b*)&LB[(MT+mf*16+l15)*72 + kg*32+quad*8];
    }
#pragma unroll
    for(int nf=0;nf<2;nf++){
      bfh[nf] = *(s8b*)&LB[(2*MT+nh*32+nf*16+l15)*72 + kg*32+quad*8];
      bfl[nf] = *(s8b*)&LB[(2*MT+64+nh*32+nf*16+l15)*72 + kg*32+quad*8];
    }
    if(r+1 < rounds) gload(r+1);
#pragma unroll
    for(int mf=0;mf<MFR;mf++){
#pragma unroll
      for(int nf=0;nf<2;nf++){
        int a = mf*2+nf;
        acc[a] = __builtin_amdgcn_mfma_f32_16x16x32_bf16(afh[mf], bfh[nf], acc[a], 0,0,0);
        acc[a] = __builtin_amdgcn_mfma_f32_16x16x32_bf16(afh[mf], bfl[nf], acc[a], 0,0,0);
        acc[a] = __builtin_amdgcn_mfma_f32_16x16x32_bf16(afl[mf], bfh[nf], acc[a], 0,0,0);
      }
    }
  }
  // cross-wave K-reduce: partner wave = w^2 (same nh, other kg)
  __syncthreads();
  f4v* scr = (f4v*)LB;
#pragma unroll
  for(int f=0;f<NACC;f++) scr[(w*NACC+f)*64 + lane] = acc[f];
  __syncthreads();
  int pw = w^2;
#pragma unroll
  for(int f=0;f<NACC;f++){
    f4v o = scr[(pw*NACC+f)*64 + lane];
    acc[f] += o;
  }

  // ---- vT-block epilogue via LDS transpose (block-uniform) ----
  bool vblk = (mode == 1 && n0 >= 512) || (mode == 3 && n0 >= 256);
  if(vblk){
    __syncthreads();
    u32* tp = (u32*)LB;                // [64 n][MT+1 m]
#pragma unroll
    for(int mi=0;mi<MFH;mi++){
      int mf = kg*MFH + mi;
#pragma unroll
      for(int nf=0;nf<2;nf++){
        f4v a = acc[mf*2+nf];
#pragma unroll
        for(int rr=0;rr<4;rr++){
          int ml = mf*16 + quad*4 + rr;
          int nl = nh*32 + nf*16 + l15;
          float val = a[rr];
          if(bias) val += bias[n0 + nl];
          val *= alpha;
          ushort hh = rneu(val);
          ushort ll = rneu(val - ubf(hh));
          tp[nl*(MT+1) + ml] = (u32)hh | ((u32)ll << 16);
        }
      }
    }
    __syncthreads();
    int b = m0 >> 10;
    int mloc = m0 & 1023;
    int d0 = n0 - ((mode == 1) ? 512 : 256);
    constexpr int NPASS = (MT==64) ? 2 : 1;
#pragma unroll
    for(int pass=0; pass<NPASS; pass++){
      int row, col;
      if(MT==64){ row = (t>>3) + pass*32; col = (t&7)*8; }
      else      { row = t>>2;             col = (t&3)*8; }
      int d = d0 + row;
      u32 c0=tp[row*(MT+1)+col+0], c1=tp[row*(MT+1)+col+1], c2=tp[row*(MT+1)+col+2], c3=tp[row*(MT+1)+col+3];
      u32 c4=tp[row*(MT+1)+col+4], c5=tp[row*(MT+1)+col+5], c6=tp[row*(MT+1)+col+6], c7=tp[row*(MT+1)+col+7];
      s8b hi, lo;
      hi[0]=(short)(c0&0xffff); lo[0]=(short)(c0>>16);
      hi[1]=(short)(c1&0xffff); lo[1]=(short)(c1>>16);
      hi[2]=(short)(c2&0xffff); lo[2]=(short)(c2>>16);
      hi[3]=(short)(c3&0xffff); lo[3]=(short)(c3>>16);
      hi[4]=(short)(c4&0xffff); lo[4]=(short)(c4>>16);
      hi[5]=(short)(c5&0xffff); lo[5]=(short)(c5>>16);
      hi[6]=(short)(c6&0xffff); lo[6]=(short)(c6>>16);
      hi[7]=(short)(c7&0xffff); lo[7]=(short)(c7>>16);
      size_t go = ((size_t)((b*4 + (d>>6))*64 + (d&63)))*1024 + mloc + col;
      *(s8b*)&vth[go] = hi;
      *(s8b*)&vtl[go] = lo;
    }
    return;
  }

  // ---- normal epilogue: wave handles its mf set, its nh half ----
#pragma unroll
  for(int mi=0;mi<MFH;mi++){
    int mf = kg*MFH + mi;
#pragma unroll
    for(int nf=0;nf<2;nf++){
      f4v a = acc[mf*2+nf];
#pragma unroll
      for(int rr=0;rr<4;rr++){
        int m = m0 + mf*16 + quad*4 + rr;
        int n = n0 + nh*32 + nf*16 + l15;
        float val = a[rr];
        if(bias) val += bias[n];
        val *= alpha;
        if(mode == 1){
          // fused rotary: pair partner lives in lane l15^1
          int d = (n < 256) ? n : (n - 256);
          const float* csp = cs + (size_t)m*64 + (d & 62);
          float cc = csp[0], ssn = csp[1];
          float pv = __shfl_xor(val, 1);
          float rv = (d & 1) ? (cc*val + ssn*pv) : (cc*val - ssn*pv);
          ushort hh = rneu(rv);
          ushort* dh = (n < 256) ? Ch : keh;
          ushort* dl = (n < 256) ? Cl : kel;
          size_t gi = (size_t)m*256 + d;
          dh[gi] = hh; dl[gi] = rneu(rv - ubf(hh));
        } else if(mode == 3){
          ushort hh = rneu(val);
          Ch[(size_t)m*256 + n] = hh;
          Cl[(size_t)m*256 + n] = rneu(val - ubf(hh));
        } else if(mode == 4){
          ushort hh = rneu(val);
          size_t gi = wofs4 + (size_t)m*512 + n;
          Ch[gi] = hh;
          Cl[gi] = rneu(val - ubf(hh));
        } else {
          if(C){
            size_t ci = (size_t)m*ldc + n;
            if(accum) val += C[ci];
            C[ci] = val;
          }
          if(Ch){
            ushort hh = rneu(val);
            Ch[(size_t)m*lds + n] = hh;
            Cl[(size_t)m*lds + n] = rneu(val - ubf(hh));
          }
        }
      }
    }
  }
}

// ---------------- MFMA flash attention, KV-chunked, split outputs ----------------
// Ps folded into wave-w's 16-row slice of Kh (K tile dead after QK^T).
// LDS = 36864 B -> 4 blocks/CU (full residency at grid 16x16x4).
#define FSC 0.18033688011112042f   /* 0.125 * log2(e) */
__global__ __launch_bounds__(256)
void k_flashmx(const ushort* __restrict__ qh_, const ushort* __restrict__ ql_,
               const ushort* __restrict__ kh_, const ushort* __restrict__ kl_,
               const ushort* __restrict__ vth_, const ushort* __restrict__ vtl_,
               ushort* __restrict__ cth, ushort* __restrict__ ctl, int bxor,
               float* __restrict__ PO, float* __restrict__ PML, int nch){
  int qt = blockIdx.x, z = blockIdx.y, ch = blockIdx.z;
  int b = z>>2, h = z&3;
  int bk = b ^ bxor;
  __shared__ __align__(16) ushort Kh[64][72], Kl[64][72], Vh[64][72], Vl[64][72];
  int t = threadIdx.x, w = t>>6, lane = t&63, quad = lane>>4, l15 = lane&15;
  ushort* Psw = &Kh[w*16][0];          // wave-private 16x72 slice of Kh
  s8b qfh[2], qfl[2];
  {
    size_t row = (size_t)b*1024 + qt*64 + w*16 + l15;
    const ushort* qrh = qh_ + row*256 + h*64;
    const ushort* qrl = ql_ + row*256 + h*64;
    qfh[0] = *(const s8b*)(qrh + quad*8);
    qfh[1] = *(const s8b*)(qrh + 32 + quad*8);
    qfl[0] = *(const s8b*)(qrl + quad*8);
    qfl[1] = *(const s8b*)(qrl + 32 + quad*8);
  }
  float m_i[4] = {-1e30f,-1e30f,-1e30f,-1e30f};
  float l_i[4] = {0.f,0.f,0.f,0.f};
  f4v O[4];
  f4v zz = {0.f,0.f,0.f,0.f};
#pragma unroll
  for(int dt=0;dt<4;dt++) O[dt] = zz;

  s8b rK0,rK1,rK2,rK3, rV0,rV1,rV2,rV3;
  auto stage_load = [&](int kt){
#pragma unroll
    for(int i=0;i<4;i++){
      int c = t + i*256;
      int half = c>>9, row = (c>>3)&63, o8 = (c&7)*8;
      const s8b* src = (const s8b*)((half ? kl_ : kh_) +
                       ((size_t)(bk*1024 + kt*64 + row))*256 + h*64 + o8);
      if(i==0) rK0=*src; else if(i==1) rK1=*src; else if(i==2) rK2=*src; else rK3=*src;
    }
#pragma unroll
    for(int i=0;i<4;i++){
      int c = t + i*256;
      int half = c>>9, d = (c>>3)&63, o8 = (c&7)*8;
      const s8b* src = (const s8b*)((half ? vtl_ : vth_) +
                       ((size_t)((bk*4+h)*64 + d))*1024 + kt*64 + o8);
      if(i==0) rV0=*src; else if(i==1) rV1=*src; else if(i==2) rV2=*src; else rV3=*src;
    }
  };
  auto stage_write = [&](){
#pragma unroll
    for(int i=0;i<4;i++){
      int c = t + i*256;
      int half = c>>9, row = (c>>3)&63, o8 = (c&7)*8;
      s8b v = (i==0)?rK0:(i==1)?rK1:(i==2)?rK2:rK3;
      if(half) *(s8b*)&Kl[row][o8] = v;
      else     *(s8b*)&Kh[row][o8] = v;
    }
#pragma unroll
    for(int i=0;i<4;i++){
      int c = t + i*256;
      int half = c>>9, d = (c>>3)&63, o8 = (c&7)*8;
      s8b v = (i==0)?rV0:(i==1)?rV1:(i==2)?rV2:rV3;
      if(half) *(s8b*)&Vl[d][o8] = v;
      else     *(s8b*)&Vh[d][o8] = v;
    }
  };

  int ktn = 16/nch;
  int kt0 = ch*ktn;
  stage_load(kt0);
  for(int kt=kt0; kt<kt0+ktn; kt++){
    __syncthreads();
    stage_write();
    __syncthreads();
    if(kt+1 < kt0+ktn) stage_load(kt+1);
    f4v s[4];
#pragma unroll
    for(int nt=0;nt<4;nt++) s[nt] = zz;
#pragma unroll
    for(int nt=0;nt<4;nt++){
#pragma unroll
      for(int k2=0;k2<2;k2++){
        s8b fbh = *(s8b*)&Kh[nt*16+l15][k2*32 + quad*8];
        s8b fbl = *(s8b*)&Kl[nt*16+l15][k2*32 + quad*8];
        s[nt] = __builtin_amdgcn_mfma_f32_16x16x32_bf16(qfh[k2], fbh, s[nt], 0,0,0);
        s[nt] = __builtin_amdgcn_mfma_f32_16x16x32_bf16(qfh[k2], fbl, s[nt], 0,0,0);
        s[nt] = __builtin_amdgcn_mfma_f32_16x16x32_bf16(qfl[k2], fbh, s[nt], 0,0,0);
      }
    }
    __syncthreads();   // all K reads done; Kh slices become P storage
#pragma unroll
    for(int rr=0;rr<4;rr++){
      float v0=s[0][rr]*FSC, v1=s[1][rr]*FSC, v2=s[2][rr]*FSC, v3=s[3][rr]*FSC;
      float mx = fmaxf(fmaxf(v0,v1), fmaxf(v2,v3));
      mx = fmaxf(mx, __shfl_xor(mx,1));
      mx = fmaxf(mx, __shfl_xor(mx,2));
      mx = fmaxf(mx, __shfl_xor(mx,4));
      mx = fmaxf(mx, __shfl_xor(mx,8));
      float mnew = fmaxf(m_i[rr], mx);
      float al = fexp2(m_i[rr] - mnew);
      float p0 = fexp2(v0-mnew), p1 = fexp2(v1-mnew), p2 = fexp2(v2-mnew), p3 = fexp2(v3-mnew);
      float ls = p0+p1+p2+p3;
      ls += __shfl_xor(ls,1);
      ls += __shfl_xor(ls,2);
      ls += __shfl_xor(ls,4);
      ls += __shfl_xor(ls,8);
      l_i[rr] = l_i[rr]*al + ls;
      m_i[rr] = mnew;
#pragma unroll
      for(int dt=0;dt<4;dt++) O[dt][rr] *= al;
      int prow = quad*4 + rr;
      Psw[prow*72 +  0 + l15] = rneu(p0);
      Psw[prow*72 + 16 + l15] = rneu(p1);
      Psw[prow*72 + 32 + l15] = rneu(p2);
      Psw[prow*72 + 48 + l15] = rneu(p3);
    }
    s8b pf0 = *(s8b*)&Psw[l15*72 + quad*8];
    s8b pf1 = *(s8b*)&Psw[l15*72 + 32 + quad*8];
#pragma unroll
    for(int dt=0;dt<4;dt++){
#pragma unroll
      for(int k2=0;k2<2;k2++){
        s8b fvh = *(s8b*)&Vh[dt*16+l15][k2*32 + quad*8];
        s8b fvl = *(s8b*)&Vl[dt*16+l15][k2*32 + quad*8];
        s8b pf = k2 ? pf1 : pf0;
        O[dt] = __builtin_amdgcn_mfma_f32_16x16x32_bf16(pf, fvh, O[dt], 0,0,0);
        O[dt] = __builtin_amdgcn_mfma_f32_16x16x32_bf16(pf, fvl, O[dt], 0,0,0);
      }
    }
  }
  if(nch == 1){
#pragma unroll
    for(int rr=0;rr<4;rr++){
      float inv = 1.f / l_i[rr];
      int row = qt*64 + w*16 + quad*4 + rr;
#pragma unroll
      for(int dt=0;dt<4;dt++){
        float val = O[dt][rr]*inv;
        size_t gi = ((size_t)b*1024 + row)*256 + h*64 + dt*16 + l15;
        ushort hh = rneu(val);
        cth[gi] = hh; ctl[gi] = rneu(val - ubf(hh));
      }
    }
  } else {
    size_t tb = (size_t)(z*16+qt)*nch + ch;
    float* po  = PO  + tb*4096;
    float* pml = PML + tb*128;
#pragma unroll
    for(int rr=0;rr<4;rr++){
      int row = w*16 + quad*4 + rr;
#pragma unroll
      for(int dt=0;dt<4;dt++){
        po[row*64 + dt*16 + l15] = O[dt][rr];
      }
      if(l15 == 0){
        pml[row]      = m_i[rr];
        pml[64 + row] = l_i[rr];
      }
    }
  }
}

// merge NCH=4 partials -> split bf16 output
__global__ __launch_bounds__(256)
void k_fmerge(const float* __restrict__ PO, const float* __restrict__ PML,
              ushort* __restrict__ cth, ushort* __restrict__ ctl){
  int qt = blockIdx.x, z = blockIdx.y;
  int b = z>>2, h = z&3;
  int t = threadIdx.x;
  int row = t>>2, dg = (t&3)*16;
  size_t tb0 = (size_t)(z*16+qt)*4;
  float m0 = PML[(tb0+0)*128 + row], m1 = PML[(tb0+1)*128 + row];
  float m2 = PML[(tb0+2)*128 + row], m3 = PML[(tb0+3)*128 + row];
  float M = fmaxf(fmaxf(m0,m1), fmaxf(m2,m3));
  float w0 = fexp2(m0-M), w1 = fexp2(m1-M), w2 = fexp2(m2-M), w3 = fexp2(m3-M);
  float L = PML[(tb0+0)*128 + 64 + row]*w0 + PML[(tb0+1)*128 + 64 + row]*w1
          + PML[(tb0+2)*128 + 64 + row]*w2 + PML[(tb0+3)*128 + 64 + row]*w3;
  float inv = 1.f/L;
  const f4v* p0 = (const f4v*)(PO + (tb0+0)*4096 + row*64 + dg);
  const f4v* p1 = (const f4v*)(PO + (tb0+1)*4096 + row*64 + dg);
  const f4v* p2 = (const f4v*)(PO + (tb0+2)*4096 + row*64 + dg);
  const f4v* p3 = (const f4v*)(PO + (tb0+3)*4096 + row*64 + dg);
  size_t gi = ((size_t)b*1024 + qt*64 + row)*256 + h*64 + dg;
#pragma unroll
  for(int j=0;j<4;j++){
    f4v o = p0[j]*w0 + p1[j]*w1 + p2[j]*w2 + p3[j]*w3;
#pragma unroll
    for(int e=0;e<4;e++){
      float val = o[e]*inv;
      ushort hh = rneu(val);
      cth[gi + j*4 + e] = hh;
      ctl[gi + j*4 + e] = rneu(val - ubf(hh));
    }
  }
}

// ---------------- LN(512)+GELU -> splits (wave-shuffle reduce) ----------------
template<typename TIN>
__device__ void ln2_body(const float* h, ushort* hh, ushort* hl, const TIN* g, const TIN* bb){
  __shared__ float ws8[8];
  int r = blockIdx.x; int t = threadIdx.x;
  int w = t>>6, lane = t&63;
  const float* row = h + (size_t)r*512;
  float a = row[t], b_ = row[t+256];
  float s = a + b_;
#pragma unroll
  for(int off=1; off<64; off<<=1) s += __shfl_xor(s, off);
  if(lane==0) ws8[w] = s;
  __syncthreads();
  float mean = (ws8[0]+ws8[1]+ws8[2]+ws8[3])*(1.f/512.f);
  float da = a-mean, db = b_-mean;
  float v = da*da + db*db;
#pragma unroll
  for(int off=1; off<64; off<<=1) v += __shfl_xor(v, off);
  if(lane==0) ws8[4+w] = v;
  __syncthreads();
  float rstd = rsqrtf((ws8[4]+ws8[5]+ws8[6]+ws8[7])*(1.f/512.f) + 1e-5f);
  float na = da*rstd*tofl(g[t])     + tofl(bb[t]);
  float nb = db*rstd*tofl(g[t+256]) + tofl(bb[t+256]);
  float ga = 0.5f*na*(1.f + erff(na*0.70710678f));
  float gb = 0.5f*nb*(1.f + erff(nb*0.70710678f));
  size_t base = (size_t)r*512;
  ushort u0 = rneu(ga); hh[base+t] = u0; hl[base+t] = rneu(ga - ubf(u0));
  ushort u1 = rneu(gb); hh[base+t+256] = u1; hl[base+t+256] = rneu(gb - ubf(u1));
}
__global__ void k_ln_gelu2(const int* flag, const float* h, ushort* hh, ushort* hl,
                           const void* gb, long goff, const void* bbb, long boff){
  if(*flag) ln2_body<float>(h, hh, hl, ((const float*)gb)+goff, ((const float*)bbb)+boff);
  else      ln2_body<bf16>(h, hh, hl, ((const bf16*)gb)+goff, ((const bf16*)bbb)+boff);
}

// ---------------- match head: z = x @ mw + mb, lsg = logsig(z) --------------
template<typename TIN>
__device__ void match_body(const float* x, const TIN* mw, const TIN* mb, float* lsg){
  __shared__ __align__(16) float wsm[256];
  int t = threadIdx.x;
  wsm[t] = tofl(mw[t]);
  __syncthreads();
  int w = t>>6, lane = t&63;
  int m = blockIdx.x*4 + w;
  const float* xr = x + (size_t)m*256 + lane*4;
  f4v xv = *(const f4v*)xr;
  f4v wv = *(const f4v*)&wsm[lane*4];
  float s = xv[0]*wv[0] + xv[1]*wv[1] + xv[2]*wv[2] + xv[3]*wv[3];
#pragma unroll
  for(int off=1; off<64; off<<=1) s += __shfl_xor(s, off);
  if(lane == 0){
    float z = s + tofl(mb[0]);
    lsg[m] = fminf(z,0.f) - log1pf(expf(-fabsf(z)));
  }
}
__global__ __launch_bounds__(256)
void k_match(const int* flag, const float* x, const void* mw, const void* mb, float* lsg){
  if(*flag) match_body<float>(x, (const float*)mw, (const float*)mb, lsg);
  else      match_body<bf16>(x, (const bf16*)mw, (const bf16*)mb, lsg);
}

// ---------------- scoring ----------------
// col-LSE stage 1: grid 512 (p=blk>>8, ci=blk&255), 4 rows each, no serial chain.
__global__ __launch_bounds__(256)
void k_lse_parts(const float* __restrict__ simbase, float* __restrict__ cpm,
                 float* __restrict__ cps){
  int blk = blockIdx.x;
  int p = blk >> 8, ci = blk & 255;
  const float* sim = simbase + (size_t)p*1048576 + (size_t)ci*4*1024;
  int t = threadIdx.x;
  size_t base = (size_t)(p*256 + ci)*1024;
#pragma unroll
  for(int j=0;j<4;j++){
    int col = t + j*256;
    float v0 = sim[col], v1 = sim[1024+col], v2 = sim[2048+col], v3 = sim[3072+col];
    float mx = fmaxf(fmaxf(v0,v1), fmaxf(v2,v3));
    float sm = expf(v0-mx)+expf(v1-mx)+expf(v2-mx)+expf(v3-mx);
    cpm[base+col] = mx;
    cps[base+col] = sm;
  }
}
// col-LSE stage 2: tree merge. grid 128 (p = blk>>6, colgroup = blk&63).
// 16 threads/col x 16 chunks each, then LDS (m,s) tree reduce.
__global__ __launch_bounds__(256)
void k_lse_merge(const float* __restrict__ cpm, const float* __restrict__ cps,
                 float* __restrict__ clseb){
  __shared__ float Rm[16][16], Rs[16][16];
  int blk = blockIdx.x;
  int p = blk >> 6, cg = blk & 63;
  int t = threadIdx.x;
  int c = t & 15, s = t >> 4;
  int col = cg*16 + c;
  size_t base = (size_t)p*256*1024 + col;
  float M = -1e30f;
#pragma unroll
  for(int k=0;k<16;k++) M = fmaxf(M, cpm[base + (size_t)(s*16+k)*1024]);
  float S = 0.f;
#pragma unroll
  for(int k=0;k<16;k++){
    size_t idx = base + (size_t)(s*16+k)*1024;
    S += cps[idx] * expf(cpm[idx] - M);
  }
  Rm[s][c] = M; Rs[s][c] = S; __syncthreads();
  for(int off=8; off>0; off>>=1){
    if(s < off){
      float m2 = Rm[s+off][c], s2 = Rs[s+off][c];
      float m1 = Rm[s][c], s1 = Rs[s][c];
      float m = fmaxf(m1, m2);
      Rm[s][c] = m;
      Rs[s][c] = s1*expf(m1-m) + s2*expf(m2-m);
    }
    __syncthreads();
  }
  if(s == 0) clseb[p*1024 + col] = Rm[0][c] + logf(Rs[0][c]);
}

// final transform with FUSED row-LSE + fused row argmax (p==0 rows feed topk)
__global__ __launch_bounds__(256)
void k_final2r(float* __restrict__ out,
               const float* __restrict__ clse, const float* __restrict__ lsg,
               int* __restrict__ m0, float* __restrict__ msc){
  __shared__ float ws4[4];
  __shared__ float bsum[4];
  int blk = blockIdx.x;                 // 0..2047 = p*1024 + n
  int p = blk >> 10, n = blk & 1023;
  int t = threadIdx.x;
  int w = t>>6, lane = t&63;
  size_t base = (size_t)blk*1024;
  float v0 = out[base+t], v1 = out[base+t+256], v2 = out[base+t+512], v3 = out[base+t+768];
  // row max
  float mx = fmaxf(fmaxf(v0,v1),fmaxf(v2,v3));
#pragma unroll
  for(int off=1; off<64; off<<=1) mx = fmaxf(mx, __shfl_xor(mx, off));
  if(lane==0) ws4[w] = mx;
  __syncthreads();
  float bm = fmaxf(fmaxf(ws4[0],ws4[1]),fmaxf(ws4[2],ws4[3]));
  // row sum(exp)
  float s = expf(v0-bm)+expf(v1-bm)+expf(v2-bm)+expf(v3-bm);
#pragma unroll
  for(int off=1; off<64; off<<=1) s += __shfl_xor(s, off);
  if(lane==0) bsum[w] = s;
  __syncthreads();
  float rl = bm + logf(bsum[0]+bsum[1]+bsum[2]+bsum[3]);
  float lgn = lsg[p*2048 + n];
  const float* lgm = lsg + p*2048 + 1024;
  const float* cl = clse + p*1024;
  float bv = -1e30f; int bi = 0;
  float nv;
  int m;
  m = t;     nv = 2.f*v0 - rl - cl[m] + lgn + lgm[m]; out[base+m] = nv; if(nv > bv){ bv = nv; bi = m; }
  m = t+256; nv = 2.f*v1 - rl - cl[m] + lgn + lgm[m]; out[base+m] = nv; if(nv > bv){ bv = nv; bi = m; }
  m = t+512; nv = 2.f*v2 - rl - cl[m] + lgn + lgm[m]; out[base+m] = nv; if(nv > bv){ bv = nv; bi = m; }
  m = t+768; nv = 2.f*v3 - rl - cl[m] + lgn + lgm[m]; out[base+m] = nv; if(nv > bv){ bv = nv; bi = m; }
  if(p) return;
#pragma unroll
  for(int off=1; off<64; off<<=1){
    float v2_ = __shfl_xor(bv, off); int i2 = __shfl_xor(bi, off);
    if(v2_ > bv || (v2_ == bv && i2 < bi)){ bv = v2_; bi = i2; }
  }
  __shared__ float wv[4]; __shared__ int wi[4];
  if(lane==0){ wv[w]=bv; wi[w]=bi; }
  __syncthreads();
  if(t==0){
#pragma unroll
    for(int k=1;k<4;k++){
      if(wv[k] > wv[0] || (wv[k]==wv[0] && wi[k] < wi[0])){ wv[0]=wv[k]; wi[0]=wi[k]; }
    }
    m0[n] = wi[0]; msc[n] = expf(wv[0]);
  }
}

// col-argmax stage 1: grid 256, 4 rows each, strict > in ascending row order.
__global__ __launch_bounds__(256)
void k_amax_parts(const float* __restrict__ sc, float* __restrict__ apv,
                  int* __restrict__ api){
  int ci = blockIdx.x;
  const float* base = sc + (size_t)ci*4*1024;
  int t = threadIdx.x;
  size_t ob = (size_t)ci*1024;
#pragma unroll
  for(int j=0;j<4;j++){
    int col = t + j*256;
    float bv = base[col]; int bi = ci*4;
    float v1 = base[1024+col]; if(v1 > bv){ bv = v1; bi = ci*4+1; }
    float v2 = base[2048+col]; if(v2 > bv){ bv = v2; bi = ci*4+2; }
    float v3 = base[3072+col]; if(v3 > bv){ bv = v3; bi = ci*4+3; }
    apv[ob+col] = bv; api[ob+col] = bi;
  }
}
// col-argmax stage 2: tree merge, ascending chunk order (lowest n wins ties).
// grid 64; 16 threads/col x 16 chunks each.
__global__ __launch_bounds__(256)
void k_amax_merge(const float* __restrict__ apv, const int* __restrict__ api,
                  int* __restrict__ m1){
  __shared__ float Rv[16][16]; __shared__ int Ri[16][16];
  int t = threadIdx.x;
  int c = t & 15, s = t >> 4;
  int col = blockIdx.x*16 + c;
  float bv = -1e30f; int bi = 0;
#pragma unroll
  for(int k=0;k<16;k++){
    size_t idx = (size_t)(s*16+k)*1024 + col;
    float v = apv[idx];
    if(v > bv){ bv = v; bi = api[idx]; }
  }
  Rv[s][c]=bv; Ri[s][c]=bi; __syncthreads();
  for(int off=8; off>0; off>>=1){
    if(s < off){
      if(Rv[s+off][c] > Rv[s][c]){ Rv[s][c]=Rv[s+off][c]; Ri[s][c]=Ri[s+off][c]; }
    }
    __syncthreads();
  }
  if(s == 0) m1[col] = Ri[0][c];
}

// ---------------- topk via global rank (parallel, exact tie semantics) -------
__global__ __launch_bounds__(128)
void k_topk(const int* __restrict__ m0, const int* __restrict__ m1,
            const float* __restrict__ msc, float* __restrict__ out){
  __shared__ float V[1024];
  int t = threadIdx.x;
  for(int i2=t; i2<1024; i2+=128){
    float mv = msc[i2];
    V[i2] = (mv > 0.1f && m1[m0[i2]] == i2) ? mv : 0.f;
  }
  __syncthreads();
  int i = blockIdx.x*128 + t;
  float vi = V[i];
  int r = 0;
#pragma unroll 8
  for(int j=0;j<1024;j++){
    float vj = V[j];
    r += (vj > vi || (vj == vi && j < i)) ? 1 : 0;
  }
  if(r < 50){
    out[2*Nc*Nc + r*3 + 0] = 0.f;
    out[2*Nc*Nc + r*3 + 1] = (float)i;
    out[2*Nc*Nc + r*3 + 2] = (float)m0[i];
    out[2*Nc*Nc + 150 + r] = vi;
  }
}

// ---------------- host ----------------
extern "C" void kernel_launch(void* const* d_in, const int* in_sizes, int n_in,
                              void* d_out, int out_size, void* d_ws, size_t ws_size,
                              hipStream_t stream){
  const void* kpts    = d_in[0];
  const void* desc    = d_in[1];
  const void* Wr      = d_in[2];
  const void* sWqkv_w = d_in[3];
  const void* sWqkv_b = d_in[4];
  const void* sOut_w  = d_in[5];
  const void* sOut_b  = d_in[6];
  const void* sF1_w   = d_in[7];
  const void* sF1_b   = d_in[8];
  const void* sLN_g   = d_in[9];
  const void* sLN_b   = d_in[10];
  const void* sF2_w   = d_in[11];
  const void* sF2_b   = d_in[12];
  const void* cQK_w   = d_in[13];
  const void* cQK_b   = d_in[14];
  const void* cV_w    = d_in[15];
  const void* cV_b    = d_in[16];
  const void* cOut_w  = d_in[17];
  const void* cOut_b  = d_in[18];
  const void* cF1_w   = d_in[19];
  const void* cF1_b   = d_in[20];
  const void* cLN_g   = d_in[21];
  const void* cLN_b   = d_in[22];
  const void* cF2_w   = d_in[23];
  const void* cF2_b   = d_in[24];
  const void* fp_w    = d_in[25];
  const void* fp_b    = d_in[26];
  const void* match_w = d_in[27];
  const void* match_b = d_in[28];

  float* ws  = (float*)d_ws;
  float* out = (float*)d_out;
  int* flag = (int*)d_ws;
  float* zbuf = ws + 64;
  float* clse = ws + 6208;
  float* msc  = ws + 12352;
  int*   m0i  = (int*)(ws + 13376);
  int*   m1i  = (int*)(ws + 14400);

  bool presplit = ws_size >= (size_t)20759552*4 + 1024;
  size_t wW = presplit ? 5603328 : 622592;
  size_t wB = presplit ? 32768   : 4096;

  size_t o = 16384;
  ushort* WH = (ushort*)(ws + o); o += wW;
  ushort* WL = (ushort*)(ws + o); o += wW;
  float*  WB = ws + o;            o += wB;
  ushort* fpWH = (ushort*)(ws + o); o += 32768;
  ushort* fpWL = (ushort*)(ws + o); o += 32768;
  float*  fpB  = ws + o;            o += 1024;
  float*  x  = ws + o;              o += 1048576;
  ushort* xh = (ushort*)(ws + o);   o += 524288;
  ushort* xl = (ushort*)(ws + o);   o += 524288;
  float*  hbuf = ws + o;            o += 2097152;
  ushort* qsh = (ushort*)(ws + o);  o += 524288;
  ushort* qsl = (ushort*)(ws + o);  o += 524288;
  ushort* ksh = (ushort*)(ws + o);  o += 524288;
  ushort* ksl = (ushort*)(ws + o);  o += 524288;
  ushort* vth = (ushort*)(ws + o);  o += 524288;
  ushort* vtl = (ushort*)(ws + o);  o += 524288;
  ushort* cth = (ushort*)(ws + o);  o += 524288;
  ushort* ctl = (ushort*)(ws + o);  o += 524288;
  ushort* mgh = (ushort*)(ws + o);  o += 524288;
  ushort* mgl = (ushort*)(ws + o);  o += 524288;
  ushort* hsh = qsh;
  ushort* hsl = ksh;
  ushort* mdh = cth;
  ushort* mdl = ctl;
  (void)mgh; (void)mgl;

  // rotary cos/sin table lives in the (not-yet-written) output buffer
  float* cs = out;   // 4096*64 floats, overwritten by final scoring

  // flash KV-split partials (16 z * 16 qt * 4 ch): PO 4096 f32/tile, PML 128 f32/tile
  float* PO  = ws + o;  // 4194304 floats
  float* PML = ws + o + 4194304;  // 131072 floats
  int nch = (ws_size >= (size_t)(20759552 + 4194304 + 131072)*4 + 1024) ? 4 : 1;

  // scoring scratch reuses PO (flash done before scoring)
  float* cpm = PO;                    // [2][256][1024]
  float* cps = PO + 524288;           // [2][256][1024]
  float* apv = PO + 1048576;          // [256][1024]
  int*   api = (int*)(PO + 1310720);  // [256][1024]

  auto MX = [&](const ushort* Ah, const ushort* Al, const ushort* A2h, const ushort* A2l,
                int lda, const ushort* Bh, const ushort* Bl, int ldb,
                const float* bias, float alpha, float* C, int ldc, int accum,
                ushort* Ch, ushort* Cl, int lds,
                ushort* keh, ushort* kel, ushort* vh, ushort* vl,
                int M, int Nout, int K, int mode, int mt){
    dim3 g(Nout/64, M/mt);
    if(mt == 32)
      k_gemm_mxT<32><<<g, 256, 0, stream>>>(Ah,Al,A2h,A2l,lda,Bh,Bl,ldb,bias,alpha,C,ldc,accum,
                                            Ch,Cl,lds,keh,kel,cs,vh,vl,K,mode);
    else
      k_gemm_mxT<64><<<g, 256, 0, stream>>>(Ah,Al,A2h,A2l,lda,Bh,Bl,ldb,bias,alpha,C,ldc,accum,
                                            Ch,Cl,lds,keh,kel,cs,vh,vl,K,mode);
  };
  auto FLASH = [&](const ushort* qh, const ushort* ql, const ushort* kh, const ushort* kl,
                   int bxor){
    k_flashmx<<<dim3(16,16,nch), 256, 0, stream>>>(qh,ql,kh,kl,vth,vtl, cth,ctl, bxor,
                                                   PO, PML, nch);
    if(nch == 4) k_fmerge<<<dim3(16,16), 256, 0, stream>>>(PO, PML, cth, ctl);
  };
  auto FOLD = [&](int ncombo, long strW){
    k_bcomb<<<dim3(8, ncombo), 256, 0, stream>>>(WH, WL, WB, strW, presplit ? 3328 : 0);
    k_gemm_mxT<32><<<dim3(4, ncombo*16), 256, 0, stream>>>(
        WH, WL, nullptr, nullptr, 0, nullptr, nullptr, 0,
        nullptr, 1.f, nullptr, 0, 0,
        WH, WL, (int)strW, nullptr, nullptr, cs, nullptr, nullptr, 256, 4);
  };

  k_detect<<<1, 64, 0, stream>>>(sLN_g, flag);
  k_splitw<<<(65536+255)/256, 256, 0, stream>>>(flag, fp_w, 0, fpWH, fpWL, 65536);
  k_biasf<<<1, 256, 0, stream>>>(flag, fp_b, 0, fpB, 256);
  k_cast2<<<(MA*Dc+255)/256, 256, 0, stream>>>(flag, desc, x, xh, xl, MA*Dc);
  k_rotcs<<<(MA*32+255)/256, 256, 0, stream>>>(flag, kpts, Wr, cs);

  if(presplit){
    dim3 g((311296+3328+255)/256, 9);
    k_wsplit<<<g, 256, 0, stream>>>(flag, 0, 1245184, 3328,
      sWqkv_w, sOut_w, sF1_w, sF2_w, cQK_w, cV_w, cOut_w, cF1_w, cF2_w,
      sWqkv_b, sOut_b, sF1_b, sF2_b, cQK_b, cV_b, cOut_b, cF1_b, cF2_b,
      WH, WL, WB);
    FOLD(18, 1245184);
  }

  for(int i=0;i<9;i++){
    if(!presplit){
      dim3 g((311296+3328+255)/256, 1);
      k_wsplit<<<g, 256, 0, stream>>>(flag, i, 0, 0,
        sWqkv_w, sOut_w, sF1_w, sF2_w, cQK_w, cV_w, cOut_w, cF1_w, cF2_w,
        sWqkv_b, sOut_b, sF1_b, sF2_b, cQK_b, cV_b, cOut_b, cF1_b, cF2_b,
        WH, WL, WB);
      FOLD(2, 0);
    }
    const ushort* WHl = presplit ? WH + (size_t)i*1245184 : WH;
    const ushort* WLl = presplit ? WL + (size_t)i*1245184 : WL;
    const float*  WBl = presplit ? WB + (size_t)i*3328    : WB;

    // ---- self (rotary fused into QKV epilogue; out-proj folded into FFN1) ----
    MX(xh,xl,nullptr,nullptr,256, WHl+0,WLl+0,256, WBl+0, 1.f,
       nullptr,0,0, qsh,qsl,0, ksh,ksl, vth,vtl, MA,768,256, 1, 32);
    FLASH(qsh,qsl,ksh,ksl, 0);
    MX(xh,xl,cth,ctl,256, WHl+262144,WLl+262144,512, WBl+1024, 1.f,
       hbuf,512,0, nullptr,nullptr,0, nullptr,nullptr, nullptr,nullptr, MA,512,512, 0, 32);
    k_ln_gelu2<<<MA, 256, 0, stream>>>(flag, hbuf, hsh, hsl, sLN_g, (long)i*512, sLN_b, (long)i*512);
    MX(hsh,hsl,nullptr,nullptr,512, WHl+524288,WLl+524288,512, WBl+1536, 1.f,
       x,256,1, xh,xl,256, nullptr,nullptr, nullptr,nullptr, MA,256,512, 0, 32);
    // ---- cross (cQK + cV fused; out-proj folded into FFN1) ----
    MX(xh,xl,nullptr,nullptr,256, WHl+655360,WLl+655360,256, WBl+1792, 1.f,
       nullptr,0,0, qsh,qsl,0, nullptr,nullptr, vth,vtl, MA,512,256, 3, 32);
    FLASH(qsh,qsl,qsh,qsl, 1);
    MX(xh,xl,cth,ctl,256, WHl+851968,WLl+851968,512, WBl+2560, 1.f,
       hbuf,512,0, nullptr,nullptr,0, nullptr,nullptr, nullptr,nullptr, MA,512,512, 0, 32);
    k_ln_gelu2<<<MA, 256, 0, stream>>>(flag, hbuf, hsh, hsl, cLN_g, (long)i*512, cLN_b, (long)i*512);
    MX(hsh,hsl,nullptr,nullptr,512, WHl+1114112,WLl+1114112,512, WBl+3072, 1.f,
       x,256,1, xh,xl,256, nullptr,nullptr, nullptr,nullptr, MA,256,512, 0, 32);
  }

  // ---- final scoring ----
  MX(xh,xl,nullptr,nullptr,256, fpWH,fpWL,256, fpB, 0.25f,
     nullptr,0,0, mdh,mdl,256, nullptr,nullptr, nullptr,nullptr, MA,256,256, 0, 32);
  k_match<<<1024, 256, 0, stream>>>(flag, x, match_w, match_b, zbuf);
  // both sim GEMMs in one batched dispatch (mode 6)
  k_gemm_mxT<32><<<dim3(16, 64), 256, 0, stream>>>(
      mdh, mdl, nullptr, nullptr, 256,
      mdh, mdl, 256,
      nullptr, 1.f, out, 1024, 0,
      nullptr, nullptr, 0,
      nullptr, nullptr, cs, nullptr, nullptr, 256, 6);

  k_lse_parts<<<512, 256, 0, stream>>>(out, cpm, cps);
  k_lse_merge<<<128, 256, 0, stream>>>(cpm, cps, clse);
  k_final2r<<<2048, 256, 0, stream>>>(out, clse, zbuf, m0i, msc);
  k_amax_parts<<<256, 256, 0, stream>>>(out, apv, api);
  k_amax_merge<<<64, 256, 0, stream>>>(apv, api, m1i);
  k_topk<<<8, 128, 0, stream>>>(m0i, m1i, msc, out);
}